// Round 1
// 244.244 us; speedup vs baseline: 1.0511x; 1.0511x over previous
//
#include <hip/hip_runtime.h>
#include <stdint.h>

typedef unsigned short u16;
typedef unsigned int   u32;

#define NG   512
#define NPG  200
#define EPG  6400
#define NN   (NG*NPG)
#define NE_  (NG*EPG)
#define HID  128
#define HS   232          // h1s/A LDS row stride in u16 (2-way-max bank pattern, 16B aligned rows)
#define ZP   136          // Z row stride in u16
#define SR   25           // rows per slice (8 slices of 25, padded to 32 for MFMA)

__device__ __forceinline__ float bf2f(u16 b){ u32 u = ((u32)b) << 16; return __builtin_bit_cast(float, u); }
__device__ __forceinline__ u16 f2bf(float f){
    u32 u = __builtin_bit_cast(u32, f);
    u = (u + 0x7FFFu + ((u >> 16) & 1u)) >> 16;
    return (u16)u;
}

typedef __attribute__((ext_vector_type(8))) short bf16x8;
typedef __attribute__((ext_vector_type(4))) float f32x4;

// canon arena (fp32): vectors only
enum : int { cW1=0, cb1=128, cb2=256, cba=384, cbb=896, cbc=1920, cbd=2944, cWe=3456, cbe=8576, cEND=8586 };
// WTa arena (bf16 [n][k])
enum : int { T_Wa=0, T_Wb=65536, T_Wc=589824, T_Wd=1638400, T_END=2162688 };

// ---------------------------------------------------------------------------
// K_prep2: LDS-tiled transposes (coalesced read AND write) for W2,Wa..Wd,
// plus canon vector copies. flag derived per block via ballot on W1 bits.
// blocks 0..531 = transpose tiles; 532..565 = canon copies.
// ---------------------------------------------------------------------------
struct PrepIn { const void* p[14]; };

__global__ __launch_bounds__(256) void k_prep2(PrepIn in, float* __restrict__ canon,
                                               u16* __restrict__ W2T, u16* __restrict__ WTa)
{
    __shared__ u16 tile[64][72];
    __shared__ int sflag;
    const int tid = threadIdx.x;
    if (tid < 64){
        const u16* wb = (const u16*)in.p[0];
        u16 a = wb[tid], b = wb[64 + tid];
        unsigned long long m1 = __ballot((int)((a >> 7) & 0xFF) >= 0x7F);
        unsigned long long m2 = __ballot((int)((b >> 7) & 0xFF) >= 0x7F);
        if (tid == 0) sflag = (__popcll(m1) + __popcll(m2) > 4) ? 1 : 0;
    }
    __syncthreads();
    const int f = sflag;
    const int bid = blockIdx.x;

    if (bid < 532){
        const void* s; u16* dst; int K, N, t, lgn;
        if      (bid < 4)  { t = bid;       s = in.p[2];  dst = W2T;        K = 128;  N = 128;  lgn = 1; }
        else if (bid < 20) { t = bid - 4;   s = in.p[4];  dst = WTa + T_Wa; K = 128;  N = 512;  lgn = 3; }
        else if (bid < 148){ t = bid - 20;  s = in.p[6];  dst = WTa + T_Wb; K = 512;  N = 1024; lgn = 4; }
        else if (bid < 404){ t = bid - 148; s = in.p[8];  dst = WTa + T_Wc; K = 1024; N = 1024; lgn = 4; }
        else               { t = bid - 404; s = in.p[10]; dst = WTa + T_Wd; K = 1024; N = 512;  lgn = 3; }
        const int k0 = (t >> lgn) * 64, n0 = (t & ((1 << lgn) - 1)) * 64;
        #pragma unroll
        for (int i = 0; i < 16; i++){
            int idx = i*256 + tid;
            int kk = idx >> 6, nn = idx & 63;
            int si = (k0 + kk)*N + n0 + nn;
            tile[nn][kk] = f ? f2bf(((const float*)s)[si]) : ((const u16*)s)[si];
        }
        __syncthreads();
        #pragma unroll
        for (int i = 0; i < 16; i++){
            int idx = i*256 + tid;
            int nn = idx >> 6, kk = idx & 63;
            dst[(size_t)(n0 + nn)*K + k0 + kk] = tile[nn][kk];
        }
    } else {
        int i = (bid - 532)*256 + tid;
        if (i < cEND){
            const void* s; int off;
            if      (i < 128) { s = in.p[0];  off = i; }
            else if (i < 256) { s = in.p[1];  off = i - 128; }
            else if (i < 384) { s = in.p[3];  off = i - 256; }
            else if (i < 896) { s = in.p[5];  off = i - 384; }
            else if (i < 1920){ s = in.p[7];  off = i - 896; }
            else if (i < 2944){ s = in.p[9];  off = i - 1920; }
            else if (i < 3456){ s = in.p[11]; off = i - 2944; }
            else if (i < 8576){ s = in.p[12]; off = i - 3456; }
            else              { s = in.p[13]; off = i - 8576; }
            canon[i] = f ? ((const float*)s)[off] : bf2f(((const u16*)s)[off]);
        }
    }
}

// ---------------------------------------------------------------------------
// K_mega v2: ONE block per graph, 512 threads, LDS <= 80288 B so TWO blocks
// co-reside per CU (prev: 139776 B -> 1 block/CU -> barrier stalls exposed,
// VALUBusy 20%, Occupancy 22%). Changes vs v1:
//  - packed edges (s|d<<8 in u16) live in GLOBAL ws (pkG), not LDS (-25.6KB);
//    per-block re-reads are L1/L2-hot.
//  - aggregation in 8 slices of 25(pad 32) dst-rows; A(counts,bf16) and Z
//    share ONE 32xHS buffer (A dead after GEMM1) (-32.3KB vs quarter Aq+Zq).
//  - degIn/degOut packed in one u32 (in<<16|out).
//  - P4 h1s fill via ds_write_b128 (8 iters instead of 58 scalar).
// A-frag: A[m=lr][k=quad*8+j]; B-frag: B[k=quad*8+j][n=lr]; C/D: col=lr,row=quad*4+r
// ---------------------------------------------------------------------------
__global__ __launch_bounds__(512, 4) void k_mega(
    const int* __restrict__ src, const int* __restrict__ dst,
    const float* __restrict__ W1, const float* __restrict__ b1,
    const float* __restrict__ b2, const u16* __restrict__ W2T,
    float* __restrict__ hg, u16* __restrict__ pkG)
{
    __shared__ __align__(16) u16 h1s[HID*HS];      // 59392 B
    __shared__ __align__(16) u16 AZ[32*HS];        // 14848 B (A counts / Z alias)
    __shared__ u32 dio[NPG];                       // 800 B (in<<16 | out)
    __shared__ __align__(16) float sAgg[NPG];      // 800 B (becomes t in place)
    __shared__ float sVal[NPG];                    // 800 B
    __shared__ __align__(16) float iiL[NPG];       // 800 B
    __shared__ __align__(16) float ioL[NPG];       // 800 B
    __shared__ float w1L[HID], b1L[HID], b2L[HID], poolL[HID]; // 2048 B
    // total 80288 B <= 81920 -> 2 blocks/CU

    const int g = blockIdx.x, tid = threadIdx.x;
    u32* az32 = (u32*)AZ;

    if (tid < NPG){ dio[tid] = 0u; sAgg[tid] = 0.f; }
    if (tid < HID){ w1L[tid] = W1[tid]; b1L[tid] = b1[tid]; b2L[tid] = b2[tid]; poolL[tid] = 0.f; }
    __syncthreads();

    // P1: edge pairs -> pack to global ws + degrees (packed u32 atomics)
    const int ebase = g * EPG;
    const int2* s2 = (const int2*)(src + ebase);
    const int2* d2 = (const int2*)(dst + ebase);
    u32* pk2 = (u32*)(pkG + ebase);
    #pragma unroll
    for (int i = 0; i < (EPG/2 + 511)/512; i++){   // 7 iters
        int e = i*512 + tid;
        if (e < EPG/2){
            int2 ss = s2[e], dd = d2[e];
            int s0 = ss.x - g*NPG, d0 = dd.x - g*NPG;
            int s1 = ss.y - g*NPG, d1 = dd.y - g*NPG;
            pk2[e] = (u32)(s0 | (d0 << 8)) | (((u32)(s1 | (d1 << 8))) << 16);
            atomicAdd(&dio[s0], 1u);       atomicAdd(&dio[d0], 0x10000u);
            atomicAdd(&dio[s1], 1u);       atomicAdd(&dio[d1], 0x10000u);
        }
    }
    __syncthreads();

    // P2: scale factors
    if (tid < NPG){
        u32 u = dio[tid];
        float din = (float)(u >> 16), dout = (float)(u & 0xFFFFu);
        float ii = rsqrtf(fmaxf(din, 1.f));
        float io = rsqrtf(fmaxf(dout, 1.f));
        iiL[tid] = ii; ioL[tid] = io;
        sVal[tid] = din * io;              // h0 = in_deg; s = h0*inv_out
    }
    __syncthreads();

    // P3: layer-1 scalar aggregation (re-read packed edges, L1/L2-hot)
    #pragma unroll
    for (int i = 0; i < (EPG/2 + 511)/512; i++){
        int e = i*512 + tid;
        if (e < EPG/2){
            u32 u = pk2[e];
            atomicAdd(&sAgg[(u >> 8) & 0xFFu], sVal[u & 0xFFu]);
            atomicAdd(&sAgg[u >> 24],          sVal[(u >> 16) & 0xFFu]);
        }
    }
    __syncthreads();
    if (tid < NPG) sAgg[tid] *= iiL[tid];  // sAgg now holds t
    __syncthreads();

    // P4: h1s[c][v] = bf16( relu(t*w1+b1) * io ), zero-pad v in [200,HS)
    // vectorized: 8 v per thread-iter, ds_write_b128. 29 groups/row (HS=232=29*8).
    #pragma unroll 2
    for (int i = 0; i < 8; i++){
        int idx8 = i*512 + tid;
        if (idx8 < 128*29){
            int c  = idx8 / 29;
            int v0 = (idx8 - c*29) * 8;
            bf16x8 out = {0,0,0,0,0,0,0,0};
            if (v0 < NPG){                 // v0 multiple of 8; 200%8==0 -> clean split
                float w1c = w1L[c], b1c = b1L[c];
                float4 ta = *(const float4*)&sAgg[v0];
                float4 tb = *(const float4*)&sAgg[v0 + 4];
                float4 ia = *(const float4*)&ioL[v0];
                float4 ib = *(const float4*)&ioL[v0 + 4];
                float tt[8]  = {ta.x, ta.y, ta.z, ta.w, tb.x, tb.y, tb.z, tb.w};
                float io8[8] = {ia.x, ia.y, ia.z, ia.w, ib.x, ib.y, ib.z, ib.w};
                #pragma unroll
                for (int j = 0; j < 8; j++)
                    out[j] = (short)f2bf(fmaxf(fmaf(tt[j], w1c, b1c), 0.f) * io8[j]);
            }
            *(bf16x8*)&h1s[c*HS + v0] = out;
        }
    }
    __syncthreads();

    const int w = tid >> 6, lane = tid & 63;
    const int lr = lane & 15, quad = lane >> 4;
    const f32x4 fz = {0.f, 0.f, 0.f, 0.f};
    const int wm  = w >> 1, wn  = w & 1;   // GEMM1 wave grid: 4(c/32) x 2(v/16)
    const int wm2 = w >> 2, wn2 = w & 3;   // GEMM2 wave grid: 2(v/16) x 4(cout/32)
    u16* Zs = AZ;                          // Z aliases A (A dead after GEMM1)

    // P5: 8 slices of 25 dst-rows
    for (int q = 0; q < 8; q++){
        // 5a: zero A
        uint4* a4 = (uint4*)AZ;
        #pragma unroll
        for (int i = 0; i < 2; i++){
            int idx = i*512 + tid;
            if (idx < 32*HS/8) a4[idx] = make_uint4(0,0,0,0);
        }
        __syncthreads();
        // 5b: scatter counts (slice filter: one sub+cmp per edge)
        #pragma unroll
        for (int i = 0; i < (EPG/2 + 511)/512; i++){
            int e = i*512 + tid;
            if (e < EPG/2){
                u32 u = pk2[e];
                int s0 = u & 0xFF,         d0 = (u >> 8) & 0xFF;
                int s1 = (u >> 16) & 0xFF, d1 = u >> 24;
                int r0 = d0 - q*SR, r1 = d1 - q*SR;
                if ((u32)r0 < (u32)SR){
                    int idx = r0*HS + s0;
                    atomicAdd(&az32[idx >> 1], 1u << (16*(idx & 1)));
                }
                if ((u32)r1 < (u32)SR){
                    int idx = r1*HS + s1;
                    atomicAdd(&az32[idx >> 1], 1u << (16*(idx & 1)));
                }
            }
        }
        __syncthreads();
        // 5c: counts -> bf16 (small ints: exact)
        #pragma unroll 2
        for (int i = 0; i < 8; i++){
            int idx = i*512 + tid;
            if (idx < 32*HS/2){
                u32 wv = az32[idx];
                if (wv)
                    az32[idx] = (u32)f2bf((float)(wv & 0xFFFFu)) | ((u32)f2bf((float)(wv >> 16)) << 16);
            }
        }
        __syncthreads();

        // 5d: GEMM1: Z^T(c x v) = h1s(128 x 224) @ A^T(224 x 32), all frags LDS
        f32x4 acc[2] = {fz, fz};
        #pragma unroll
        for (int ks = 0; ks < 7; ks++){
            bf16x8 af0 = *(const bf16x8*)&h1s[(wm*32 +      lr)*HS + ks*32 + quad*8];
            bf16x8 af1 = *(const bf16x8*)&h1s[(wm*32 + 16 + lr)*HS + ks*32 + quad*8];
            bf16x8 bfr = *(const bf16x8*)&AZ [(wn*16 +      lr)*HS + ks*32 + quad*8];
            acc[0] = __builtin_amdgcn_mfma_f32_16x16x32_bf16(af0, bfr, acc[0], 0, 0, 0);
            acc[1] = __builtin_amdgcn_mfma_f32_16x16x32_bf16(af1, bfr, acc[1], 0, 0, 0);
        }
        __syncthreads();   // all A reads done before Z overwrites the buffer

        // 5e: write Z (un-transpose): Z[v][c]
        #pragma unroll
        for (int mi = 0; mi < 2; mi++){
            int vq = wn*16 + lr;
            int c0 = wm*32 + mi*16 + quad*4;
            u16 z0 = f2bf(acc[mi][0]), z1 = f2bf(acc[mi][1]);
            u16 z2 = f2bf(acc[mi][2]), z3 = f2bf(acc[mi][3]);
            uint2 pk = { (u32)z0 | ((u32)z1 << 16), (u32)z2 | ((u32)z3 << 16) };
            *(uint2*)&Zs[vq*ZP + c0] = pk;
        }
        __syncthreads();

        // 5f: GEMM2: H(32 x 128) = Z(32x128) @ W2 (W2T global, L1-hot)
        f32x4 acc2[2] = {fz, fz};
        #pragma unroll
        for (int ks = 0; ks < 4; ks++){
            bf16x8 za  = *(const bf16x8*)&Zs[(wm2*16 + lr)*ZP + ks*32 + quad*8];
            bf16x8 wb0 = *(const bf16x8*)&W2T[(size_t)(wn2*32 +      lr)*HID + ks*32 + quad*8];
            bf16x8 wb1 = *(const bf16x8*)&W2T[(size_t)(wn2*32 + 16 + lr)*HID + ks*32 + quad*8];
            acc2[0] = __builtin_amdgcn_mfma_f32_16x16x32_bf16(za, wb0, acc2[0], 0, 0, 0);
            acc2[1] = __builtin_amdgcn_mfma_f32_16x16x32_bf16(za, wb1, acc2[1], 0, 0, 0);
        }
        // 5g: epilogue: h2 = relu(H*invIn + b2); pool
        #pragma unroll
        for (int nt = 0; nt < 2; nt++){
            int cout = wn2*32 + nt*16 + lr;
            float sacc = 0.f;
            #pragma unroll
            for (int r = 0; r < 4; r++){
                int vq = wm2*16 + quad*4 + r;
                if (vq < SR)
                    sacc += fmaxf(fmaf(acc2[nt][r], iiL[q*SR + vq], b2L[cout]), 0.f);
            }
            atomicAdd(&poolL[cout], sacc);
        }
        __syncthreads();   // Z reads done before next slice zeroes AZ
    }

    // P6: hg
    if (tid < HID) hg[(size_t)g*HID + tid] = poolL[tid] * (1.f / NPG);
}

// ---------------------------------------------------------------------------
// MLP layer, MFMA hi/lo bf16 split, 2-way K-split + explicit A/B prefetch.
// Block 512 thr = 8 waves (2kz x 2wm x 2wn); tile 32x64; LDS store+add merge.
// ---------------------------------------------------------------------------
template<int K, bool AF32>
__global__ __launch_bounds__(512) void k_mlp5(
    const void* __restrict__ Ahi_, const u16* __restrict__ Alo,
    const u16* __restrict__ WT, const float* __restrict__ bias,
    u16* __restrict__ Ohi, u16* __restrict__ Olo, int Nc)
{
    constexpr int ITERS = K / 64;
    __shared__ __align__(16) float red[32][68];

    const int tid = threadIdx.x;
    const int w = tid >> 6, lane = tid & 63;
    const int kz = w >> 2, wm = (w >> 1) & 1, wn = w & 1;
    const int lr = lane & 15, quad = lane >> 4;
    const int row0 = blockIdx.x * 32, col0 = blockIdx.y * 64;
    const int m = row0 + wm*16 + lr;
    const int k0 = kz * (K/2);

    const float* Af = (const float*)Ahi_;
    const u16*   Ah = (const u16*)Ahi_;

    auto loadA = [&](int it, bf16x8& hi, bf16x8& lo){
        const int kk = k0 + it*32 + quad*8;
        if constexpr (AF32){
            float xs[8];
            *(float4*)&xs[0] = *(const float4*)&Af[(size_t)m*K + kk];
            *(float4*)&xs[4] = *(const float4*)&Af[(size_t)m*K + kk + 4];
            #pragma unroll
            for (int j = 0; j < 8; j++){
                u16 hh = f2bf(xs[j]);
                hi[j] = (short)hh;
                lo[j] = (short)f2bf(xs[j] - bf2f(hh));
            }
        } else {
            hi = *(const bf16x8*)&Ah[(size_t)m*K + kk];
            lo = *(const bf16x8*)&Alo[(size_t)m*K + kk];
        }
    };
    auto loadB = [&](int it, bf16x8* b){
        const int kk = k0 + it*32 + quad*8;
        #pragma unroll
        for (int nt = 0; nt < 2; nt++){
            int n = col0 + wn*32 + nt*16 + lr;
            b[nt] = *(const bf16x8*)&WT[(size_t)n*K + kk];
        }
    };

    const f32x4 fz = {0.f, 0.f, 0.f, 0.f};
    f32x4 acc[2] = {fz, fz};
    bf16x8 chi, clo, cb[2], nhi, nlo, nb[2];
    loadA(0, chi, clo); loadB(0, cb);
    #pragma unroll 2
    for (int it = 0; it < ITERS; it++){
        if (it + 1 < ITERS){ loadA(it+1, nhi, nlo); loadB(it+1, nb); }
        #pragma unroll
        for (int nt = 0; nt < 2; nt++){
            acc[nt] = __builtin_amdgcn_mfma_f32_16x16x32_bf16(chi, cb[nt], acc[nt], 0, 0, 0);
            acc[nt] = __builtin_amdgcn_mfma_f32_16x16x32_bf16(clo, cb[nt], acc[nt], 0, 0, 0);
        }
        chi = nhi; clo = nlo; cb[0] = nb[0]; cb[1] = nb[1];
    }

    if (kz == 1){
        #pragma unroll
        for (int nt = 0; nt < 2; nt++)
            #pragma unroll
            for (int r = 0; r < 4; r++)
                red[wm*16 + quad*4 + r][wn*32 + nt*16 + lr] = acc[nt][r];
    }
    __syncthreads();
    if (kz == 0){
        #pragma unroll
        for (int nt = 0; nt < 2; nt++)
            #pragma unroll
            for (int r = 0; r < 4; r++){
                int rr = wm*16 + quad*4 + r;
                int cc = wn*32 + nt*16 + lr;
                float v = acc[nt][r] + red[rr][cc] + bias[col0 + cc];
                v = fmaxf(v, 0.f);
                u16 hh = f2bf(v);
                size_t go = (size_t)(row0 + rr) * Nc + col0 + cc;
                Ohi[go] = hh;
                Olo[go] = f2bf(v - bf2f(hh));
            }
    }
}

// ---------------------------------------------------------------------------
// head: logits = (X4hi+X4lo) @ We + be; softmax -> out (dtype derived inline)
// ---------------------------------------------------------------------------
__global__ __launch_bounds__(64) void k_head(
    const u16* __restrict__ Xhi, const u16* __restrict__ Xlo,
    const float* __restrict__ We, const float* __restrict__ be,
    void* __restrict__ out, const u16* __restrict__ w1bits)
{
    const int g = blockIdx.x, lane = threadIdx.x;
    u16 a = w1bits[lane], b = w1bits[64 + lane];
    unsigned long long m1 = __ballot((int)((a >> 7) & 0xFF) >= 0x7F);
    unsigned long long m2 = __ballot((int)((b >> 7) & 0xFF) >= 0x7F);
    const int f = (__popcll(m1) + __popcll(m2) > 4) ? 1 : 0;

    float part[10];
    #pragma unroll
    for (int c = 0; c < 10; c++) part[c] = 0.f;
    for (int k = lane; k < 512; k += 64){
        float x = bf2f(Xhi[(size_t)g*512 + k]) + bf2f(Xlo[(size_t)g*512 + k]);
        #pragma unroll
        for (int c = 0; c < 10; c++) part[c] = fmaf(x, We[k*10 + c], part[c]);
    }
    #pragma unroll
    for (int c = 0; c < 10; c++){
        float v = part[c];
        for (int off = 32; off > 0; off >>= 1) v += __shfl_down(v, off);
        part[c] = v;
    }
    if (lane == 0){
        #pragma unroll
        for (int c = 0; c < 10; c++) part[c] += be[c];
        float m = part[0];
        #pragma unroll
        for (int c = 1; c < 10; c++) m = fmaxf(m, part[c]);
        float e[10], s = 0.f;
        #pragma unroll
        for (int c = 0; c < 10; c++){ e[c] = __expf(part[c] - m); s += e[c]; }
        float inv = 1.f / s;
        #pragma unroll
        for (int c = 0; c < 10; c++){
            float p = e[c] * inv;
            if (f) ((float*)out)[g*10 + c] = p;
            else   ((u16*)out)[g*10 + c]  = f2bf(p);
        }
    }
}

// ---------------------------------------------------------------------------
extern "C" void kernel_launch(void* const* d_in, const int* in_sizes, int n_in,
                              void* d_out, int out_size, void* d_ws, size_t ws_size,
                              hipStream_t stream)
{
    const int* src = (const int*)d_in[0];
    const int* dst = (const int*)d_in[1];

    char* ws = (char*)d_ws;
    size_t o = 0;
    float* canon    = (float*)(ws + o); o += ((size_t)cEND * 4 + 15) & ~(size_t)15;
    u16*   W2T      = (u16*)  (ws + o); o += (size_t)HID * HID * 2;
    u16*   WTa      = (u16*)  (ws + o); o += ((size_t)T_END * 2 + 15) & ~(size_t)15;
    float* hg       = (float*)(ws + o); o += (size_t)NG * HID * 4;
    u16*   X1hi     = (u16*)  (ws + o); o += (size_t)NG * 512 * 2;
    u16*   X1lo     = (u16*)  (ws + o); o += (size_t)NG * 512 * 2;
    u16*   X2hi     = (u16*)  (ws + o); o += (size_t)NG * 1024 * 2;
    u16*   X2lo     = (u16*)  (ws + o); o += (size_t)NG * 1024 * 2;
    u16*   X3hi     = (u16*)  (ws + o); o += (size_t)NG * 1024 * 2;
    u16*   X3lo     = (u16*)  (ws + o); o += (size_t)NG * 1024 * 2;
    u16*   X4hi     = (u16*)  (ws + o); o += (size_t)NG * 512 * 2;
    u16*   X4lo     = (u16*)  (ws + o); o += (size_t)NG * 512 * 2;
    u16*   pkG      = (u16*)  (ws + o); o += (size_t)NE_ * 2;
    (void)ws_size; (void)in_sizes; (void)n_in; (void)out_size;

    // prep: tiled transposes + canon copies
    PrepIn pin;
    for (int i = 0; i < 14; i++) pin.p[i] = d_in[2 + i];
    k_prep2<<<dim3(566), dim3(256), 0, stream>>>(pin, canon, W2T, WTa);

    const float *W1 = canon+cW1, *b1 = canon+cb1, *b2 = canon+cb2;
    const float *ba = canon+cba, *bb = canon+cbb, *bc = canon+cbc, *bd = canon+cbd;
    const float *We = canon+cWe, *be = canon+cbe;

    // mega: whole graph path (edges -> hg), 2 blocks/CU resident
    k_mega<<<dim3(NG), dim3(512), 0, stream>>>(src, dst, W1, b1, b2, W2T, hg, pkG);

    // MLP: MFMA hi/lo-split layers with prefetch
    k_mlp5<128,  true ><<<dim3(16, 8),  dim3(512), 0, stream>>>(hg,   nullptr, WTa + T_Wa, ba, X1hi, X1lo, 512);
    k_mlp5<512,  false><<<dim3(16, 16), dim3(512), 0, stream>>>(X1hi, X1lo,    WTa + T_Wb, bb, X2hi, X2lo, 1024);
    k_mlp5<1024, false><<<dim3(16, 16), dim3(512), 0, stream>>>(X2hi, X2lo,    WTa + T_Wc, bc, X3hi, X3lo, 1024);
    k_mlp5<1024, false><<<dim3(16, 8),  dim3(512), 0, stream>>>(X3hi, X3lo,    WTa + T_Wd, bd, X4hi, X4lo, 512);

    // head + softmax
    k_head<<<dim3(NG), dim3(64), 0, stream>>>(X4hi, X4lo, We, be, d_out, (const u16*)d_in[2]);
}

// Round 2
// 222.049 us; speedup vs baseline: 1.1561x; 1.1000x over previous
//
#include <hip/hip_runtime.h>
#include <stdint.h>

typedef unsigned short u16;
typedef unsigned char  u8;
typedef unsigned int   u32;

#define NG   512
#define NPG  200
#define EPG  6400
#define NN   (NG*NPG)
#define NE_  (NG*EPG)
#define HID  128
#define HS   232          // h1s LDS row stride in u16 (16B-aligned rows, benign banking)
#define ZP   136          // Z row stride in u16 (4-dword stride -> conflict-free b128)
#define SR   50           // rows per slice (4 slices of 50, padded to 64 for MFMA)
#define SPAD 232          // count-matrix row stride (u8)
#define GROWS 216         // per-graph row allocation (200 real + slack for padded reads)

__device__ __forceinline__ float bf2f(u16 b){ u32 u = ((u32)b) << 16; return __builtin_bit_cast(float, u); }
__device__ __forceinline__ u16 f2bf(float f){
    u32 u = __builtin_bit_cast(u32, f);
    u = (u + 0x7FFFu + ((u >> 16) & 1u)) >> 16;
    return (u16)u;
}

typedef __attribute__((ext_vector_type(8))) short bf16x8;
typedef __attribute__((ext_vector_type(4))) float f32x4;

// canon arena (fp32): vectors only
enum : int { cW1=0, cb1=128, cb2=256, cba=384, cbb=896, cbc=1920, cbd=2944, cWe=3456, cbe=8576, cEND=8586 };
// WTa arena (bf16 [n][k])
enum : int { T_Wa=0, T_Wb=65536, T_Wc=589824, T_Wd=1638400, T_END=2162688 };

// ---------------------------------------------------------------------------
// K_prep2: LDS-tiled transposes (coalesced read AND write) for W2,Wa..Wd,
// plus canon vector copies. flag derived per block via ballot on W1 bits.
// blocks 0..531 = transpose tiles; 532..565 = canon copies.
// ---------------------------------------------------------------------------
struct PrepIn { const void* p[14]; };

__global__ __launch_bounds__(256) void k_prep2(PrepIn in, float* __restrict__ canon,
                                               u16* __restrict__ W2T, u16* __restrict__ WTa)
{
    __shared__ u16 tile[64][72];
    __shared__ int sflag;
    const int tid = threadIdx.x;
    if (tid < 64){
        const u16* wb = (const u16*)in.p[0];
        u16 a = wb[tid], b = wb[64 + tid];
        unsigned long long m1 = __ballot((int)((a >> 7) & 0xFF) >= 0x7F);
        unsigned long long m2 = __ballot((int)((b >> 7) & 0xFF) >= 0x7F);
        if (tid == 0) sflag = (__popcll(m1) + __popcll(m2) > 4) ? 1 : 0;
    }
    __syncthreads();
    const int f = sflag;
    const int bid = blockIdx.x;

    if (bid < 532){
        const void* s; u16* dst; int K, N, t, lgn;
        if      (bid < 4)  { t = bid;       s = in.p[2];  dst = W2T;        K = 128;  N = 128;  lgn = 1; }
        else if (bid < 20) { t = bid - 4;   s = in.p[4];  dst = WTa + T_Wa; K = 128;  N = 512;  lgn = 3; }
        else if (bid < 148){ t = bid - 20;  s = in.p[6];  dst = WTa + T_Wb; K = 512;  N = 1024; lgn = 4; }
        else if (bid < 404){ t = bid - 148; s = in.p[8];  dst = WTa + T_Wc; K = 1024; N = 1024; lgn = 4; }
        else               { t = bid - 404; s = in.p[10]; dst = WTa + T_Wd; K = 1024; N = 512;  lgn = 3; }
        const int k0 = (t >> lgn) * 64, n0 = (t & ((1 << lgn) - 1)) * 64;
        #pragma unroll
        for (int i = 0; i < 16; i++){
            int idx = i*256 + tid;
            int kk = idx >> 6, nn = idx & 63;
            int si = (k0 + kk)*N + n0 + nn;
            tile[nn][kk] = f ? f2bf(((const float*)s)[si]) : ((const u16*)s)[si];
        }
        __syncthreads();
        #pragma unroll
        for (int i = 0; i < 16; i++){
            int idx = i*256 + tid;
            int nn = idx >> 6, kk = idx & 63;
            dst[(size_t)(n0 + nn)*K + k0 + kk] = tile[nn][kk];
        }
    } else {
        int i = (bid - 532)*256 + tid;
        if (i < cEND){
            const void* s; int off;
            if      (i < 128) { s = in.p[0];  off = i; }
            else if (i < 256) { s = in.p[1];  off = i - 128; }
            else if (i < 384) { s = in.p[3];  off = i - 256; }
            else if (i < 896) { s = in.p[5];  off = i - 384; }
            else if (i < 1920){ s = in.p[7];  off = i - 896; }
            else if (i < 2944){ s = in.p[9];  off = i - 1920; }
            else if (i < 3456){ s = in.p[11]; off = i - 2944; }
            else if (i < 8576){ s = in.p[12]; off = i - 3456; }
            else              { s = in.p[13]; off = i - 8576; }
            canon[i] = f ? ((const float*)s)[off] : bf2f(((const u16*)s)[off]);
        }
    }
}

// ---------------------------------------------------------------------------
// K_build: per-graph block, ALL atomic/scatter work lives here where small
// LDS (~50 KB -> 3 blocks/CU, 24 waves) lets TLP hide the latency.
// Outputs: AG8[g][216][232] u8 count matrix (rows 0..199 written, zero-padded
// cols; slack rows read-only garbage, guarded downstream) and
// tioG[g][608] = {t[200], io[200], ii[200]}.
// Edges are read ONCE into registers and reused for both atomic passes.
// ---------------------------------------------------------------------------
__global__ __launch_bounds__(512, 6) void k_build(
    const int* __restrict__ src, const int* __restrict__ dst,
    u8* __restrict__ AG8, float* __restrict__ tioG)
{
    __shared__ __align__(16) u32 cnt[NPG*SPAD/4];   // 46400 B u8 counts
    __shared__ u32 dio[NPG];                        // in<<16 | out
    __shared__ float sAgg[NPG], sVal[NPG], ioL[NPG], iiL[NPG];

    const int g = blockIdx.x, tid = threadIdx.x;

    uint4* c4 = (uint4*)cnt;
    for (int i = tid; i < NPG*SPAD/16; i += 512) c4[i] = make_uint4(0,0,0,0);
    if (tid < NPG){ dio[tid] = 0u; sAgg[tid] = 0.f; }
    __syncthreads();

    const int ebase = g * EPG;
    const int2* s2 = (const int2*)(src + ebase);
    const int2* d2 = (const int2*)(dst + ebase);
    int2 ss[7], dd[7];
    #pragma unroll
    for (int i = 0; i < 7; i++){
        int e = i*512 + tid;
        if (e < EPG/2){ ss[i] = s2[e]; dd[i] = d2[e]; }
    }
    // pass 1: degrees + counts
    #pragma unroll
    for (int i = 0; i < 7; i++){
        int e = i*512 + tid;
        if (e < EPG/2){
            int s0 = ss[i].x - g*NPG, d0 = dd[i].x - g*NPG;
            int s1 = ss[i].y - g*NPG, d1 = dd[i].y - g*NPG;
            atomicAdd(&dio[s0], 1u);  atomicAdd(&dio[d0], 0x10000u);
            atomicAdd(&dio[s1], 1u);  atomicAdd(&dio[d1], 0x10000u);
            int i0 = d0*SPAD + s0, i1 = d1*SPAD + s1;
            atomicAdd(&cnt[i0 >> 2], 1u << (8*(i0 & 3)));
            atomicAdd(&cnt[i1 >> 2], 1u << (8*(i1 & 3)));
        }
    }
    __syncthreads();
    if (tid < NPG){
        u32 u = dio[tid];
        float din = (float)(u >> 16), dout = (float)(u & 0xFFFFu);
        float ii = rsqrtf(fmaxf(din, 1.f));
        float io = rsqrtf(fmaxf(dout, 1.f));
        iiL[tid] = ii; ioL[tid] = io;
        sVal[tid] = din * io;          // h0 = in_deg; s = h0*inv_out
    }
    __syncthreads();
    // pass 2: layer-1 scalar aggregation (edges from registers)
    #pragma unroll
    for (int i = 0; i < 7; i++){
        int e = i*512 + tid;
        if (e < EPG/2){
            int s0 = ss[i].x - g*NPG, d0 = dd[i].x - g*NPG;
            int s1 = ss[i].y - g*NPG, d1 = dd[i].y - g*NPG;
            atomicAdd(&sAgg[d0], sVal[s0]);
            atomicAdd(&sAgg[d1], sVal[s1]);
        }
    }
    __syncthreads();
    if (tid < NPG){
        tioG[(size_t)g*608 + tid]       = sAgg[tid] * iiL[tid];   // t
        tioG[(size_t)g*608 + 200 + tid] = ioL[tid];
        tioG[(size_t)g*608 + 400 + tid] = iiL[tid];
    }
    uint4* dq = (uint4*)(AG8 + (size_t)g*GROWS*SPAD);
    for (int i = tid; i < NPG*SPAD/16; i += 512) dq[i] = c4[i];
}

// ---------------------------------------------------------------------------
// K_mega v3: pure-GEMM slice loop. No edges, no atomics, no scatter phases.
//  P0: load t/io/ii (t,io staged in the Zs buffer: dead before first Zwrite).
//  P4: h1s[c][v] = bf16( relu(t*w1+b1)*io ), vectorized b128 stores.
//  P5: 4 slices of 50 dst rows (padded to 64):
//     GEMM1 Z^T(c x v) = h1s @ A^T; A-counts read from global AG8 as u8 and
//     converted to bf16 IN REGISTERS (exact: ints<256 truncate to bf16).
//     GEMM2 H = Z @ W2 (W2T global, L1-hot); relu/ii/pool epilogue.
//  2 barriers per slice (was 5), ~170 DS ops/thread (was ~700).
// Padded rows (v>=50) read slack/garbage u8 -> finite floats; epilogue guards
// vq<SR so they never reach the output.
// A-frag: A[m=lr][k=quad*8+j]; B-frag: B[k=quad*8+j][n=lr]; C/D: col=lr,row=quad*4+r
// ---------------------------------------------------------------------------
__global__ __launch_bounds__(512, 4) void k_mega(
    const u8* __restrict__ AG8, const float* __restrict__ tioG,
    const float* __restrict__ W1, const float* __restrict__ b1,
    const float* __restrict__ b2, const u16* __restrict__ W2T,
    float* __restrict__ hg)
{
    __shared__ __align__(16) u16 h1s[HID*HS];      // 59392 B
    __shared__ __align__(16) u16 Zs[64*ZP];        // 17408 B (aliases t/io staging)
    __shared__ __align__(16) float iiL[NPG];
    __shared__ float w1L[HID], b1L[HID], b2L[HID], poolL[HID];
    // total 79648 B <= 81920 -> 2 blocks/CU

    float* tL  = (float*)Zs;                       // 200 floats (dead after P4)
    float* ioL = (float*)Zs + NPG;                 // 200 floats (dead after P4)

    const int g = blockIdx.x, tid = threadIdx.x;
    if (tid < NPG){
        tL[tid]  = tioG[(size_t)g*608 + tid];
        ioL[tid] = tioG[(size_t)g*608 + 200 + tid];
        iiL[tid] = tioG[(size_t)g*608 + 400 + tid];
    }
    if (tid < HID){ w1L[tid] = W1[tid]; b1L[tid] = b1[tid]; b2L[tid] = b2[tid]; poolL[tid] = 0.f; }
    __syncthreads();

    // P4: h1s[c][v] = bf16( relu(t*w1+b1) * io ), zero-pad v in [200,HS)
    #pragma unroll 2
    for (int i = 0; i < 8; i++){
        int idx8 = i*512 + tid;
        if (idx8 < 128*29){
            int c  = idx8 / 29;
            int v0 = (idx8 - c*29) * 8;
            bf16x8 out = {0,0,0,0,0,0,0,0};
            if (v0 < NPG){                 // v0 multiple of 8; 200%8==0 -> clean split
                float w1c = w1L[c], b1c = b1L[c];
                float4 ta = *(const float4*)&tL[v0];
                float4 tb = *(const float4*)&tL[v0 + 4];
                float4 ia = *(const float4*)&ioL[v0];
                float4 ib = *(const float4*)&ioL[v0 + 4];
                float tt[8]  = {ta.x, ta.y, ta.z, ta.w, tb.x, tb.y, tb.z, tb.w};
                float io8[8] = {ia.x, ia.y, ia.z, ia.w, ib.x, ib.y, ib.z, ib.w};
                #pragma unroll
                for (int j = 0; j < 8; j++)
                    out[j] = (short)f2bf(fmaxf(fmaf(tt[j], w1c, b1c), 0.f) * io8[j]);
            }
            *(bf16x8*)&h1s[c*HS + v0] = out;
        }
    }
    __syncthreads();

    const int w = tid >> 6, lane = tid & 63;
    const int lr = lane & 15, quad = lane >> 4;
    const f32x4 fz = {0.f, 0.f, 0.f, 0.f};
    const int wm = w >> 2, wn = w & 3;   // GEMM1: 2(c/64) x 4(v/16); GEMM2: 2(v/32) x 4(cout/32)
    const u8* Abase = AG8 + (size_t)g*GROWS*SPAD;

    for (int q = 0; q < 4; q++){
        // GEMM1: Z^T(128c x 64v) = h1s(128x224) @ A^T(224x64)
        const u8* brow = Abase + (size_t)(q*SR + wn*16 + lr)*SPAD;
        uint2 braw[7];
        #pragma unroll
        for (int ks = 0; ks < 7; ks++)
            braw[ks] = *(const uint2*)(brow + ks*32 + quad*8);
        f32x4 acc[4] = {fz, fz, fz, fz};
        #pragma unroll
        for (int ks = 0; ks < 7; ks++){
            u32 lo = braw[ks].x, hi = braw[ks].y;
            bf16x8 bfr;
            #pragma unroll
            for (int j = 0; j < 4; j++){   // u8 -> bf16 exact (truncate: ints<256 have zero low mantissa)
                bfr[j]   = (short)(u16)(__builtin_bit_cast(u32, (float)((lo >> (8*j)) & 0xFFu)) >> 16);
                bfr[j+4] = (short)(u16)(__builtin_bit_cast(u32, (float)((hi >> (8*j)) & 0xFFu)) >> 16);
            }
            #pragma unroll
            for (int mi = 0; mi < 4; mi++){
                bf16x8 af = *(const bf16x8*)&h1s[(wm*64 + mi*16 + lr)*HS + ks*32 + quad*8];
                acc[mi] = __builtin_amdgcn_mfma_f32_16x16x32_bf16(af, bfr, acc[mi], 0, 0, 0);
            }
        }
        __syncthreads();   // prev slice's GEMM2 Zs reads done (q>0) / P4 done (q=0)

        // write Z (un-transpose): Zs[v][c]
        #pragma unroll
        for (int mi = 0; mi < 4; mi++){
            int vq = wn*16 + lr;
            int c0 = wm*64 + mi*16 + quad*4;
            u16 z0 = f2bf(acc[mi][0]), z1 = f2bf(acc[mi][1]);
            u16 z2 = f2bf(acc[mi][2]), z3 = f2bf(acc[mi][3]);
            uint2 pk = { (u32)z0 | ((u32)z1 << 16), (u32)z2 | ((u32)z3 << 16) };
            *(uint2*)&Zs[vq*ZP + c0] = pk;
        }
        __syncthreads();

        // GEMM2: H(64v x 128cout) = Zs(64x128) @ W2 (W2T global, L1-hot)
        f32x4 acc2[2][2] = {{fz, fz}, {fz, fz}};
        #pragma unroll
        for (int ks = 0; ks < 4; ks++){
            bf16x8 za[2], wb[2];
            #pragma unroll
            for (int mi = 0; mi < 2; mi++)
                za[mi] = *(const bf16x8*)&Zs[(wm*32 + mi*16 + lr)*ZP + ks*32 + quad*8];
            #pragma unroll
            for (int nt = 0; nt < 2; nt++)
                wb[nt] = *(const bf16x8*)&W2T[(size_t)(wn*32 + nt*16 + lr)*HID + ks*32 + quad*8];
            #pragma unroll
            for (int mi = 0; mi < 2; mi++)
                #pragma unroll
                for (int nt = 0; nt < 2; nt++)
                    acc2[mi][nt] = __builtin_amdgcn_mfma_f32_16x16x32_bf16(
                        za[mi], wb[nt], acc2[mi][nt], 0, 0, 0);
        }
        // epilogue: h2 = relu(H*invIn + b2); pool
        #pragma unroll
        for (int mi = 0; mi < 2; mi++)
            #pragma unroll
            for (int nt = 0; nt < 2; nt++){
                int cout = wn*32 + nt*16 + lr;
                float s = 0.f;
                #pragma unroll
                for (int r = 0; r < 4; r++){
                    int vq = wm*32 + mi*16 + quad*4 + r;
                    if (vq < SR)
                        s += fmaxf(fmaf(acc2[mi][nt][r], iiL[q*SR + vq], b2L[cout]), 0.f);
                }
                atomicAdd(&poolL[cout], s);
            }
    }
    __syncthreads();

    // P6: hg
    if (tid < HID) hg[(size_t)g*HID + tid] = poolL[tid] * (1.f / NPG);
}

// ---------------------------------------------------------------------------
// MLP layer, MFMA hi/lo bf16 split, 2-way K-split + explicit A/B prefetch.
// Block 512 thr = 8 waves (2kz x 2wm x 2wn); tile 32x64; LDS store+add merge.
// ---------------------------------------------------------------------------
template<int K, bool AF32>
__global__ __launch_bounds__(512) void k_mlp5(
    const void* __restrict__ Ahi_, const u16* __restrict__ Alo,
    const u16* __restrict__ WT, const float* __restrict__ bias,
    u16* __restrict__ Ohi, u16* __restrict__ Olo, int Nc)
{
    constexpr int ITERS = K / 64;
    __shared__ __align__(16) float red[32][68];

    const int tid = threadIdx.x;
    const int w = tid >> 6, lane = tid & 63;
    const int kz = w >> 2, wm = (w >> 1) & 1, wn = w & 1;
    const int lr = lane & 15, quad = lane >> 4;
    const int row0 = blockIdx.x * 32, col0 = blockIdx.y * 64;
    const int m = row0 + wm*16 + lr;
    const int k0 = kz * (K/2);

    const float* Af = (const float*)Ahi_;
    const u16*   Ah = (const u16*)Ahi_;

    auto loadA = [&](int it, bf16x8& hi, bf16x8& lo){
        const int kk = k0 + it*32 + quad*8;
        if constexpr (AF32){
            float xs[8];
            *(float4*)&xs[0] = *(const float4*)&Af[(size_t)m*K + kk];
            *(float4*)&xs[4] = *(const float4*)&Af[(size_t)m*K + kk + 4];
            #pragma unroll
            for (int j = 0; j < 8; j++){
                u16 hh = f2bf(xs[j]);
                hi[j] = (short)hh;
                lo[j] = (short)f2bf(xs[j] - bf2f(hh));
            }
        } else {
            hi = *(const bf16x8*)&Ah[(size_t)m*K + kk];
            lo = *(const bf16x8*)&Alo[(size_t)m*K + kk];
        }
    };
    auto loadB = [&](int it, bf16x8* b){
        const int kk = k0 + it*32 + quad*8;
        #pragma unroll
        for (int nt = 0; nt < 2; nt++){
            int n = col0 + wn*32 + nt*16 + lr;
            b[nt] = *(const bf16x8*)&WT[(size_t)n*K + kk];
        }
    };

    const f32x4 fz = {0.f, 0.f, 0.f, 0.f};
    f32x4 acc[2] = {fz, fz};
    bf16x8 chi, clo, cb[2], nhi, nlo, nb[2];
    loadA(0, chi, clo); loadB(0, cb);
    #pragma unroll 2
    for (int it = 0; it < ITERS; it++){
        if (it + 1 < ITERS){ loadA(it+1, nhi, nlo); loadB(it+1, nb); }
        #pragma unroll
        for (int nt = 0; nt < 2; nt++){
            acc[nt] = __builtin_amdgcn_mfma_f32_16x16x32_bf16(chi, cb[nt], acc[nt], 0, 0, 0);
            acc[nt] = __builtin_amdgcn_mfma_f32_16x16x32_bf16(clo, cb[nt], acc[nt], 0, 0, 0);
        }
        chi = nhi; clo = nlo; cb[0] = nb[0]; cb[1] = nb[1];
    }

    if (kz == 1){
        #pragma unroll
        for (int nt = 0; nt < 2; nt++)
            #pragma unroll
            for (int r = 0; r < 4; r++)
                red[wm*16 + quad*4 + r][wn*32 + nt*16 + lr] = acc[nt][r];
    }
    __syncthreads();
    if (kz == 0){
        #pragma unroll
        for (int nt = 0; nt < 2; nt++)
            #pragma unroll
            for (int r = 0; r < 4; r++){
                int rr = wm*16 + quad*4 + r;
                int cc = wn*32 + nt*16 + lr;
                float v = acc[nt][r] + red[rr][cc] + bias[col0 + cc];
                v = fmaxf(v, 0.f);
                u16 hh = f2bf(v);
                size_t go = (size_t)(row0 + rr) * Nc + col0 + cc;
                Ohi[go] = hh;
                Olo[go] = f2bf(v - bf2f(hh));
            }
    }
}

// ---------------------------------------------------------------------------
// head: logits = (X4hi+X4lo) @ We + be; softmax -> out (dtype derived inline)
// ---------------------------------------------------------------------------
__global__ __launch_bounds__(64) void k_head(
    const u16* __restrict__ Xhi, const u16* __restrict__ Xlo,
    const float* __restrict__ We, const float* __restrict__ be,
    void* __restrict__ out, const u16* __restrict__ w1bits)
{
    const int g = blockIdx.x, lane = threadIdx.x;
    u16 a = w1bits[lane], b = w1bits[64 + lane];
    unsigned long long m1 = __ballot((int)((a >> 7) & 0xFF) >= 0x7F);
    unsigned long long m2 = __ballot((int)((b >> 7) & 0xFF) >= 0x7F);
    const int f = (__popcll(m1) + __popcll(m2) > 4) ? 1 : 0;

    float part[10];
    #pragma unroll
    for (int c = 0; c < 10; c++) part[c] = 0.f;
    for (int k = lane; k < 512; k += 64){
        float x = bf2f(Xhi[(size_t)g*512 + k]) + bf2f(Xlo[(size_t)g*512 + k]);
        #pragma unroll
        for (int c = 0; c < 10; c++) part[c] = fmaf(x, We[k*10 + c], part[c]);
    }
    #pragma unroll
    for (int c = 0; c < 10; c++){
        float v = part[c];
        for (int off = 32; off > 0; off >>= 1) v += __shfl_down(v, off);
        part[c] = v;
    }
    if (lane == 0){
        #pragma unroll
        for (int c = 0; c < 10; c++) part[c] += be[c];
        float m = part[0];
        #pragma unroll
        for (int c = 1; c < 10; c++) m = fmaxf(m, part[c]);
        float e[10], s = 0.f;
        #pragma unroll
        for (int c = 0; c < 10; c++){ e[c] = __expf(part[c] - m); s += e[c]; }
        float inv = 1.f / s;
        #pragma unroll
        for (int c = 0; c < 10; c++){
            float p = e[c] * inv;
            if (f) ((float*)out)[g*10 + c] = p;
            else   ((u16*)out)[g*10 + c]  = f2bf(p);
        }
    }
}

// ---------------------------------------------------------------------------
extern "C" void kernel_launch(void* const* d_in, const int* in_sizes, int n_in,
                              void* d_out, int out_size, void* d_ws, size_t ws_size,
                              hipStream_t stream)
{
    const int* src = (const int*)d_in[0];
    const int* dst = (const int*)d_in[1];

    char* ws = (char*)d_ws;
    size_t o = 0;
    float* canon    = (float*)(ws + o); o += ((size_t)cEND * 4 + 15) & ~(size_t)15;
    u16*   W2T      = (u16*)  (ws + o); o += (size_t)HID * HID * 2;
    u16*   WTa      = (u16*)  (ws + o); o += ((size_t)T_END * 2 + 15) & ~(size_t)15;
    float* hg       = (float*)(ws + o); o += (size_t)NG * HID * 4;
    u16*   X1hi     = (u16*)  (ws + o); o += (size_t)NG * 512 * 2;
    u16*   X1lo     = (u16*)  (ws + o); o += (size_t)NG * 512 * 2;
    u16*   X2hi     = (u16*)  (ws + o); o += (size_t)NG * 1024 * 2;
    u16*   X2lo     = (u16*)  (ws + o); o += (size_t)NG * 1024 * 2;
    u16*   X3hi     = (u16*)  (ws + o); o += (size_t)NG * 1024 * 2;
    u16*   X3lo     = (u16*)  (ws + o); o += (size_t)NG * 1024 * 2;
    u16*   X4hi     = (u16*)  (ws + o); o += (size_t)NG * 512 * 2;
    u16*   X4lo     = (u16*)  (ws + o); o += (size_t)NG * 512 * 2;
    o = (o + 15) & ~(size_t)15;
    u8*    AG8      = (u8*)   (ws + o); o += (size_t)NG * GROWS * SPAD;
    float* tioG     = (float*)(ws + o); o += (size_t)NG * 608 * 4;
    (void)ws_size; (void)in_sizes; (void)n_in; (void)out_size;

    // prep: tiled transposes + canon copies
    PrepIn pin;
    for (int i = 0; i < 14; i++) pin.p[i] = d_in[2 + i];
    k_prep2<<<dim3(566), dim3(256), 0, stream>>>(pin, canon, W2T, WTa);

    const float *W1 = canon+cW1, *b1 = canon+cb1, *b2 = canon+cb2;
    const float *ba = canon+cba, *bb = canon+cbb, *bc = canon+cbc, *bd = canon+cbd;
    const float *We = canon+cWe, *be = canon+cbe;

    // build: all graph-topology atomics at high occupancy (3 blocks/CU)
    k_build<<<dim3(NG), dim3(512), 0, stream>>>(src, dst, AG8, tioG);

    // mega: pure-GEMM slice loop, 2 blocks/CU
    k_mega<<<dim3(NG), dim3(512), 0, stream>>>(AG8, tioG, W1, b1, b2, W2T, hg);

    // MLP: MFMA hi/lo-split layers with prefetch
    k_mlp5<128,  true ><<<dim3(16, 8),  dim3(512), 0, stream>>>(hg,   nullptr, WTa + T_Wa, ba, X1hi, X1lo, 512);
    k_mlp5<512,  false><<<dim3(16, 16), dim3(512), 0, stream>>>(X1hi, X1lo,    WTa + T_Wb, bb, X2hi, X2lo, 1024);
    k_mlp5<1024, false><<<dim3(16, 16), dim3(512), 0, stream>>>(X2hi, X2lo,    WTa + T_Wc, bc, X3hi, X3lo, 1024);
    k_mlp5<1024, false><<<dim3(16, 8),  dim3(512), 0, stream>>>(X3hi, X3lo,    WTa + T_Wd, bd, X4hi, X4lo, 512);

    // head + softmax
    k_head<<<dim3(NG), dim3(64), 0, stream>>>(X4hi, X4lo, We, be, d_out, (const u16*)d_in[2]);
}

// Round 3
// 198.410 us; speedup vs baseline: 1.2939x; 1.1191x over previous
//
#include <hip/hip_runtime.h>
#include <stdint.h>

typedef unsigned short u16;
typedef unsigned char  u8;
typedef unsigned int   u32;

#define NG   512
#define NPG  200
#define EPG  6400
#define NN   (NG*NPG)
#define NE_  (NG*EPG)
#define HID  128
#define HS   232          // h1s LDS row stride in u16 (16B-aligned rows, benign banking)
#define ZP   136          // Z row stride in u16 (4-dword stride -> conflict-free b128)
#define SR   50           // rows per slice (4 slices of 50, padded to 64 for MFMA)
#define SPAD 232          // count-matrix row stride (u8)
#define GROWS 216         // per-graph row allocation (200 real + slack for padded reads)

__device__ __forceinline__ float bf2f(u16 b){ u32 u = ((u32)b) << 16; return __builtin_bit_cast(float, u); }
__device__ __forceinline__ u16 f2bf(float f){
    u32 u = __builtin_bit_cast(u32, f);
    u = (u + 0x7FFFu + ((u >> 16) & 1u)) >> 16;
    return (u16)u;
}

typedef __attribute__((ext_vector_type(8))) short bf16x8;
typedef __attribute__((ext_vector_type(4))) float f32x4;

// canon arena (fp32): vectors only
enum : int { cW1=0, cb1=128, cb2=256, cba=384, cbb=896, cbc=1920, cbd=2944, cWe=3456, cbe=8576, cEND=8586 };
// WTa arena (bf16 [n][k])
enum : int { T_Wa=0, T_Wb=65536, T_Wc=589824, T_Wd=1638400, T_END=2162688 };

// ---------------------------------------------------------------------------
// K_prep2: LDS-tiled transposes, both phases vectorized 4x (uint2/float4).
// blocks 0..531 = transpose tiles; 532..565 = canon copies.
// ---------------------------------------------------------------------------
struct PrepIn { const void* p[14]; };

__global__ __launch_bounds__(256) void k_prep2(PrepIn in, float* __restrict__ canon,
                                               u16* __restrict__ W2T, u16* __restrict__ WTa)
{
    __shared__ u16 tile[64][72];
    __shared__ int sflag;
    const int tid = threadIdx.x;
    if (tid < 64){
        const u16* wb = (const u16*)in.p[0];
        u16 a = wb[tid], b = wb[64 + tid];
        unsigned long long m1 = __ballot((int)((a >> 7) & 0xFF) >= 0x7F);
        unsigned long long m2 = __ballot((int)((b >> 7) & 0xFF) >= 0x7F);
        if (tid == 0) sflag = (__popcll(m1) + __popcll(m2) > 4) ? 1 : 0;
    }
    __syncthreads();
    const int f = sflag;
    const int bid = blockIdx.x;

    if (bid < 532){
        const void* s; u16* dst; int K, N, t, lgn;
        if      (bid < 4)  { t = bid;       s = in.p[2];  dst = W2T;        K = 128;  N = 128;  lgn = 1; }
        else if (bid < 20) { t = bid - 4;   s = in.p[4];  dst = WTa + T_Wa; K = 128;  N = 512;  lgn = 3; }
        else if (bid < 148){ t = bid - 20;  s = in.p[6];  dst = WTa + T_Wb; K = 512;  N = 1024; lgn = 4; }
        else if (bid < 404){ t = bid - 148; s = in.p[8];  dst = WTa + T_Wc; K = 1024; N = 1024; lgn = 4; }
        else               { t = bid - 404; s = in.p[10]; dst = WTa + T_Wd; K = 1024; N = 512;  lgn = 3; }
        const int k0 = (t >> lgn) * 64, n0 = (t & ((1 << lgn) - 1)) * 64;
        // phase 1: global -> tile, 4 u16 (or 4 f32) per thread-iter, coalesced over nn
        #pragma unroll
        for (int i = 0; i < 4; i++){
            int idx = i*256 + tid;                 // 64 kk x 16 nn-groups
            int kk = idx >> 4, nn0 = (idx & 15)*4;
            int si = (k0 + kk)*N + n0 + nn0;
            if (f){
                float4 fv = *(const float4*)&((const float*)s)[si];
                tile[nn0+0][kk] = f2bf(fv.x); tile[nn0+1][kk] = f2bf(fv.y);
                tile[nn0+2][kk] = f2bf(fv.z); tile[nn0+3][kk] = f2bf(fv.w);
            } else {
                uint2 uv = *(const uint2*)&((const u16*)s)[si];
                tile[nn0+0][kk] = (u16)(uv.x & 0xFFFF); tile[nn0+1][kk] = (u16)(uv.x >> 16);
                tile[nn0+2][kk] = (u16)(uv.y & 0xFFFF); tile[nn0+3][kk] = (u16)(uv.y >> 16);
            }
        }
        __syncthreads();
        // phase 2: tile -> global, uint2 (4 u16) per thread-iter, coalesced over kk
        #pragma unroll
        for (int i = 0; i < 4; i++){
            int idx = i*256 + tid;                 // 64 nn x 16 kk-groups
            int nn = idx >> 4, kk0 = (idx & 15)*4;
            uint2 val = *(const uint2*)&tile[nn][kk0];
            *(uint2*)&dst[(size_t)(n0 + nn)*K + k0 + kk0] = val;
        }
    } else {
        int i = (bid - 532)*256 + tid;
        if (i < cEND){
            const void* s; int off;
            if      (i < 128) { s = in.p[0];  off = i; }
            else if (i < 256) { s = in.p[1];  off = i - 128; }
            else if (i < 384) { s = in.p[3];  off = i - 256; }
            else if (i < 896) { s = in.p[5];  off = i - 384; }
            else if (i < 1920){ s = in.p[7];  off = i - 896; }
            else if (i < 2944){ s = in.p[9];  off = i - 1920; }
            else if (i < 3456){ s = in.p[11]; off = i - 2944; }
            else if (i < 8576){ s = in.p[12]; off = i - 3456; }
            else              { s = in.p[13]; off = i - 8576; }
            canon[i] = f ? ((const float*)s)[off] : bf2f(((const u16*)s)[off]);
        }
    }
}

// ---------------------------------------------------------------------------
// K_build: per-graph block; all atomic/scatter topology work at 3 blocks/CU.
// Outputs AG8[g][216][232] u8 counts + tioG[g][608] = {t, io, ii}.
// ---------------------------------------------------------------------------
__global__ __launch_bounds__(512, 6) void k_build(
    const int* __restrict__ src, const int* __restrict__ dst,
    u8* __restrict__ AG8, float* __restrict__ tioG)
{
    __shared__ __align__(16) u32 cnt[NPG*SPAD/4];   // 46400 B u8 counts
    __shared__ u32 dio[NPG];                        // in<<16 | out
    __shared__ float sAgg[NPG], sVal[NPG], ioL[NPG], iiL[NPG];

    const int g = blockIdx.x, tid = threadIdx.x;

    uint4* c4 = (uint4*)cnt;
    for (int i = tid; i < NPG*SPAD/16; i += 512) c4[i] = make_uint4(0,0,0,0);
    if (tid < NPG){ dio[tid] = 0u; sAgg[tid] = 0.f; }
    __syncthreads();

    const int ebase = g * EPG;
    const int2* s2 = (const int2*)(src + ebase);
    const int2* d2 = (const int2*)(dst + ebase);
    int2 ss[7], dd[7];
    #pragma unroll
    for (int i = 0; i < 7; i++){
        int e = i*512 + tid;
        if (e < EPG/2){ ss[i] = s2[e]; dd[i] = d2[e]; }
    }
    // pass 1: degrees + counts
    #pragma unroll
    for (int i = 0; i < 7; i++){
        int e = i*512 + tid;
        if (e < EPG/2){
            int s0 = ss[i].x - g*NPG, d0 = dd[i].x - g*NPG;
            int s1 = ss[i].y - g*NPG, d1 = dd[i].y - g*NPG;
            atomicAdd(&dio[s0], 1u);  atomicAdd(&dio[d0], 0x10000u);
            atomicAdd(&dio[s1], 1u);  atomicAdd(&dio[d1], 0x10000u);
            int i0 = d0*SPAD + s0, i1 = d1*SPAD + s1;
            atomicAdd(&cnt[i0 >> 2], 1u << (8*(i0 & 3)));
            atomicAdd(&cnt[i1 >> 2], 1u << (8*(i1 & 3)));
        }
    }
    __syncthreads();
    if (tid < NPG){
        u32 u = dio[tid];
        float din = (float)(u >> 16), dout = (float)(u & 0xFFFFu);
        float ii = rsqrtf(fmaxf(din, 1.f));
        float io = rsqrtf(fmaxf(dout, 1.f));
        iiL[tid] = ii; ioL[tid] = io;
        sVal[tid] = din * io;          // h0 = in_deg; s = h0*inv_out
    }
    __syncthreads();
    // pass 2: layer-1 scalar aggregation (edges from registers)
    #pragma unroll
    for (int i = 0; i < 7; i++){
        int e = i*512 + tid;
        if (e < EPG/2){
            int s0 = ss[i].x - g*NPG, d0 = dd[i].x - g*NPG;
            int s1 = ss[i].y - g*NPG, d1 = dd[i].y - g*NPG;
            atomicAdd(&sAgg[d0], sVal[s0]);
            atomicAdd(&sAgg[d1], sVal[s1]);
        }
    }
    __syncthreads();
    if (tid < NPG){
        tioG[(size_t)g*608 + tid]       = sAgg[tid] * iiL[tid];   // t
        tioG[(size_t)g*608 + 200 + tid] = ioL[tid];
        tioG[(size_t)g*608 + 400 + tid] = iiL[tid];
    }
    uint4* dq = (uint4*)(AG8 + (size_t)g*GROWS*SPAD);
    for (int i = tid; i < NPG*SPAD/16; i += 512) dq[i] = c4[i];
}

// ---------------------------------------------------------------------------
// K_mega v4: pure-GEMM slice loop + fused mlp_a.
//  - W2T fragments hoisted to registers ONCE (slice-invariant; was 4x reload).
//  - AG8 rows for slice q+1 prefetched during GEMM2 of slice q.
//  - pool accumulated in registers across slices; quad-shuffle reduce ->
//    2 LDS atomics per 16 lanes (was 16 contended atomics/thread).
//  - epilogue computes X1 = relu(pool/200 @ Wa + ba) directly: thread tid
//    owns column tid (512 = exactly X1 width), fp32 dot over 128 -> replaces
//    the whole k_mlp5<128> kernel at higher precision.
// A-frag: A[m=lr][k=quad*8+j]; B-frag: B[k=quad*8+j][n=lr]; C/D: col=lr,row=quad*4+r
// ---------------------------------------------------------------------------
__global__ __launch_bounds__(512, 4) void k_mega(
    const u8* __restrict__ AG8, const float* __restrict__ tioG,
    const float* __restrict__ W1, const float* __restrict__ b1,
    const float* __restrict__ b2, const u16* __restrict__ W2T,
    const u16* __restrict__ WTaA, const float* __restrict__ ba,
    u16* __restrict__ X1hi, u16* __restrict__ X1lo)
{
    __shared__ __align__(16) u16 h1s[HID*HS];      // 59392 B
    __shared__ __align__(16) u16 Zs[64*ZP];        // 17408 B (aliases t/io staging)
    __shared__ __align__(16) float iiL[NPG];
    __shared__ float w1L[HID], b1L[HID], b2L[HID], poolL[HID];
    // total 79648 B <= 81920 -> 2 blocks/CU

    float* tL  = (float*)Zs;                       // 200 floats (dead after P4)
    float* ioL = (float*)Zs + NPG;                 // 200 floats (dead after P4)

    const int g = blockIdx.x, tid = threadIdx.x;
    if (tid < NPG){
        tL[tid]  = tioG[(size_t)g*608 + tid];
        ioL[tid] = tioG[(size_t)g*608 + 200 + tid];
        iiL[tid] = tioG[(size_t)g*608 + 400 + tid];
    }
    if (tid < HID){ w1L[tid] = W1[tid]; b1L[tid] = b1[tid]; b2L[tid] = b2[tid]; poolL[tid] = 0.f; }

    const int w = tid >> 6, lane = tid & 63;
    const int lr = lane & 15, quad = lane >> 4;
    const f32x4 fz = {0.f, 0.f, 0.f, 0.f};
    const int wm = w >> 2, wn = w & 3;   // GEMM1: 2(c/64) x 4(v/16); GEMM2: 2(v/32) x 4(cout/32)
    const u8* Abase = AG8 + (size_t)g*GROWS*SPAD;

    // hoist W2T fragments (slice-invariant): 8 frags = 32 VGPR
    bf16x8 wReg[4][2];
    #pragma unroll
    for (int ks = 0; ks < 4; ks++)
        #pragma unroll
        for (int nt = 0; nt < 2; nt++)
            wReg[ks][nt] = *(const bf16x8*)&W2T[(size_t)(wn*32 + nt*16 + lr)*HID + ks*32 + quad*8];

    __syncthreads();

    // P4: h1s[c][v] = bf16( relu(t*w1+b1) * io ), zero-pad v in [200,HS)
    #pragma unroll 2
    for (int i = 0; i < 8; i++){
        int idx8 = i*512 + tid;
        if (idx8 < 128*29){
            int c  = idx8 / 29;
            int v0 = (idx8 - c*29) * 8;
            bf16x8 out = {0,0,0,0,0,0,0,0};
            if (v0 < NPG){                 // v0 multiple of 8; 200%8==0 -> clean split
                float w1c = w1L[c], b1c = b1L[c];
                float4 ta = *(const float4*)&tL[v0];
                float4 tb = *(const float4*)&tL[v0 + 4];
                float4 ia = *(const float4*)&ioL[v0];
                float4 ib = *(const float4*)&ioL[v0 + 4];
                float tt[8]  = {ta.x, ta.y, ta.z, ta.w, tb.x, tb.y, tb.z, tb.w};
                float io8[8] = {ia.x, ia.y, ia.z, ia.w, ib.x, ib.y, ib.z, ib.w};
                #pragma unroll
                for (int j = 0; j < 8; j++)
                    out[j] = (short)f2bf(fmaxf(fmaf(tt[j], w1c, b1c), 0.f) * io8[j]);
            }
            *(bf16x8*)&h1s[c*HS + v0] = out;
        }
    }
    __syncthreads();

    // per-thread invariants for GEMM2 epilogue
    const float b2c0 = b2L[wn*32 + lr], b2c1 = b2L[wn*32 + 16 + lr];
    float pacc[2] = {0.f, 0.f};

    const u8* brow0 = Abase + (size_t)(wn*16 + lr)*SPAD;
    uint2 brA[7], brB[7];
    #pragma unroll
    for (int ks = 0; ks < 7; ks++)
        brA[ks] = *(const uint2*)(brow0 + ks*32 + quad*8);

    for (int q = 0; q < 4; q++){
        // GEMM1: Z^T(128c x 64v) = h1s(128x224) @ A^T(224x64)
        f32x4 acc[4] = {fz, fz, fz, fz};
        #pragma unroll
        for (int ks = 0; ks < 7; ks++){
            u32 lo = brA[ks].x, hi = brA[ks].y;
            bf16x8 bfr;
            #pragma unroll
            for (int j = 0; j < 4; j++){   // u8 -> bf16 exact (ints<256 truncate clean)
                bfr[j]   = (short)(u16)(__builtin_bit_cast(u32, (float)((lo >> (8*j)) & 0xFFu)) >> 16);
                bfr[j+4] = (short)(u16)(__builtin_bit_cast(u32, (float)((hi >> (8*j)) & 0xFFu)) >> 16);
            }
            #pragma unroll
            for (int mi = 0; mi < 4; mi++){
                bf16x8 af = *(const bf16x8*)&h1s[(wm*64 + mi*16 + lr)*HS + ks*32 + quad*8];
                acc[mi] = __builtin_amdgcn_mfma_f32_16x16x32_bf16(af, bfr, acc[mi], 0, 0, 0);
            }
        }
        // prefetch next slice's AG8 rows (hidden under barrier + GEMM2)
        if (q < 3){
            const u8* brow = Abase + (size_t)((q+1)*SR + wn*16 + lr)*SPAD;
            #pragma unroll
            for (int ks = 0; ks < 7; ks++)
                brB[ks] = *(const uint2*)(brow + ks*32 + quad*8);
        }
        __syncthreads();   // prev GEMM2 Zs reads done (q>0) / P4 done (q=0)

        // write Z (un-transpose): Zs[v][c]
        #pragma unroll
        for (int mi = 0; mi < 4; mi++){
            int vq = wn*16 + lr;
            int c0 = wm*64 + mi*16 + quad*4;
            u16 z0 = f2bf(acc[mi][0]), z1 = f2bf(acc[mi][1]);
            u16 z2 = f2bf(acc[mi][2]), z3 = f2bf(acc[mi][3]);
            uint2 pk = { (u32)z0 | ((u32)z1 << 16), (u32)z2 | ((u32)z3 << 16) };
            *(uint2*)&Zs[vq*ZP + c0] = pk;
        }
        __syncthreads();

        // GEMM2: H(64v x 128cout) = Zs(64x128) @ W2 (B-frags from registers)
        f32x4 acc2[2][2] = {{fz, fz}, {fz, fz}};
        #pragma unroll
        for (int ks = 0; ks < 4; ks++){
            bf16x8 za[2];
            #pragma unroll
            for (int mi = 0; mi < 2; mi++)
                za[mi] = *(const bf16x8*)&Zs[(wm*32 + mi*16 + lr)*ZP + ks*32 + quad*8];
            #pragma unroll
            for (int mi = 0; mi < 2; mi++)
                #pragma unroll
                for (int nt = 0; nt < 2; nt++)
                    acc2[mi][nt] = __builtin_amdgcn_mfma_f32_16x16x32_bf16(
                        za[mi], wReg[ks][nt], acc2[mi][nt], 0, 0, 0);
        }
        // epilogue: pacc += relu(H*invIn + b2), in registers
        #pragma unroll
        for (int mi = 0; mi < 2; mi++)
            #pragma unroll
            for (int nt = 0; nt < 2; nt++){
                float b2c = nt ? b2c1 : b2c0;
                #pragma unroll
                for (int r = 0; r < 4; r++){
                    int vq = wm*32 + mi*16 + quad*4 + r;
                    if (vq < SR)
                        pacc[nt] += fmaxf(fmaf(acc2[mi][nt][r], iiL[q*SR + vq], b2c), 0.f);
                }
            }
        #pragma unroll
        for (int ks = 0; ks < 7; ks++) brA[ks] = brB[ks];
    }

    // pool reduce: quad-shuffle then 1 atomic per 16 lanes per nt (2 waves/cout)
    #pragma unroll
    for (int nt = 0; nt < 2; nt++){
        float v = pacc[nt];
        v += __shfl_down(v, 32);
        v += __shfl_down(v, 16);
        if (quad == 0) atomicAdd(&poolL[wn*32 + nt*16 + lr], v);
    }
    __syncthreads();

    // fused mlp_a: X1[g][c=tid] = relu( (pool/200) . Wa[:,c] + ba[c] ), fp32 dot
    {
        const u16* wrow = WTaA + (size_t)tid * HID;   // WTa row-major [512][128]
        float dot = 0.f;
        #pragma unroll
        for (int kk = 0; kk < HID; kk += 8){
            bf16x8 wv = *(const bf16x8*)&wrow[kk];
            float4 p0 = *(const float4*)&poolL[kk];
            float4 p1 = *(const float4*)&poolL[kk + 4];
            float pp[8] = {p0.x, p0.y, p0.z, p0.w, p1.x, p1.y, p1.z, p1.w};
            #pragma unroll
            for (int j = 0; j < 8; j++)
                dot = fmaf(pp[j], bf2f((u16)wv[j]), dot);
        }
        float v = fmaxf(dot * (1.f/NPG) + ba[tid], 0.f);
        u16 hh = f2bf(v);
        X1hi[(size_t)g*512 + tid] = hh;
        X1lo[(size_t)g*512 + tid] = f2bf(v - bf2f(hh));
    }
}

// ---------------------------------------------------------------------------
// MLP layer v6: 4-way K-split, tile 16 x (NFR*32), grid >= 512 blocks ->
// 2 blocks/CU, 16 waves/CU (old: 256 blocks, 1/CU). 8 waves = 4kz x 2wn.
// hi/lo bf16 split MFMA, depth-1 prefetch, 3-way LDS reduce + epilogue.
// ---------------------------------------------------------------------------
template<int K, int NFR>
__global__ __launch_bounds__(512) void k_mlp6(
    const u16* __restrict__ Ahi, const u16* __restrict__ Alo,
    const u16* __restrict__ WT, const float* __restrict__ bias,
    u16* __restrict__ Ohi, u16* __restrict__ Olo, int Nc)
{
    constexpr int KQ = K/4, ITERS = KQ/32, NTILE = NFR*32;
    __shared__ __align__(16) float red[3][16][68];

    const int tid = threadIdx.x;
    const int w = tid >> 6, lane = tid & 63;
    const int kz = w >> 1, wn = w & 1;
    const int lr = lane & 15, quad = lane >> 4;
    const int row0 = blockIdx.x * 16, col0 = blockIdx.y * NTILE;
    const size_t m = row0 + lr;
    const int k0 = kz * KQ;

    auto loadA = [&](int it, bf16x8& hi, bf16x8& lo){
        const int kk = k0 + it*32 + quad*8;
        hi = *(const bf16x8*)&Ahi[m*K + kk];
        lo = *(const bf16x8*)&Alo[m*K + kk];
    };
    auto loadB = [&](int it, bf16x8* b){
        const int kk = k0 + it*32 + quad*8;
        #pragma unroll
        for (int nt = 0; nt < NFR; nt++){
            int n = col0 + wn*(NFR*16) + nt*16 + lr;
            b[nt] = *(const bf16x8*)&WT[(size_t)n*K + kk];
        }
    };

    const f32x4 fz = {0.f, 0.f, 0.f, 0.f};
    f32x4 acc[NFR];
    #pragma unroll
    for (int nt = 0; nt < NFR; nt++) acc[nt] = fz;
    bf16x8 chi, clo, cb[NFR], nhi, nlo, nb[NFR];
    loadA(0, chi, clo); loadB(0, cb);
    #pragma unroll
    for (int it = 0; it < ITERS; it++){
        if (it + 1 < ITERS){ loadA(it+1, nhi, nlo); loadB(it+1, nb); }
        #pragma unroll
        for (int nt = 0; nt < NFR; nt++){
            acc[nt] = __builtin_amdgcn_mfma_f32_16x16x32_bf16(chi, cb[nt], acc[nt], 0, 0, 0);
            acc[nt] = __builtin_amdgcn_mfma_f32_16x16x32_bf16(clo, cb[nt], acc[nt], 0, 0, 0);
        }
        chi = nhi; clo = nlo;
        #pragma unroll
        for (int nt = 0; nt < NFR; nt++) cb[nt] = nb[nt];
    }

    if (kz > 0){
        #pragma unroll
        for (int nt = 0; nt < NFR; nt++)
            #pragma unroll
            for (int r = 0; r < 4; r++)
                red[kz-1][quad*4 + r][wn*(NFR*16) + nt*16 + lr] = acc[nt][r];
    }
    __syncthreads();
    if (kz == 0){
        #pragma unroll
        for (int nt = 0; nt < NFR; nt++)
            #pragma unroll
            for (int r = 0; r < 4; r++){
                int rr = quad*4 + r;
                int cc = wn*(NFR*16) + nt*16 + lr;
                float v = acc[nt][r] + red[0][rr][cc] + red[1][rr][cc] + red[2][rr][cc]
                        + bias[col0 + cc];
                v = fmaxf(v, 0.f);
                u16 hh = f2bf(v);
                size_t go = (size_t)(row0 + rr) * Nc + col0 + cc;
                Ohi[go] = hh;
                Olo[go] = f2bf(v - bf2f(hh));
            }
    }
}

// ---------------------------------------------------------------------------
// head: logits = (X4hi+X4lo) @ We + be; softmax -> out (dtype derived inline)
// ---------------------------------------------------------------------------
__global__ __launch_bounds__(64) void k_head(
    const u16* __restrict__ Xhi, const u16* __restrict__ Xlo,
    const float* __restrict__ We, const float* __restrict__ be,
    void* __restrict__ out, const u16* __restrict__ w1bits)
{
    const int g = blockIdx.x, lane = threadIdx.x;
    u16 a = w1bits[lane], b = w1bits[64 + lane];
    unsigned long long m1 = __ballot((int)((a >> 7) & 0xFF) >= 0x7F);
    unsigned long long m2 = __ballot((int)((b >> 7) & 0xFF) >= 0x7F);
    const int f = (__popcll(m1) + __popcll(m2) > 4) ? 1 : 0;

    float part[10];
    #pragma unroll
    for (int c = 0; c < 10; c++) part[c] = 0.f;
    for (int k = lane; k < 512; k += 64){
        float x = bf2f(Xhi[(size_t)g*512 + k]) + bf2f(Xlo[(size_t)g*512 + k]);
        #pragma unroll
        for (int c = 0; c < 10; c++) part[c] = fmaf(x, We[k*10 + c], part[c]);
    }
    #pragma unroll
    for (int c = 0; c < 10; c++){
        float v = part[c];
        for (int off = 32; off > 0; off >>= 1) v += __shfl_down(v, off);
        part[c] = v;
    }
    if (lane == 0){
        #pragma unroll
        for (int c = 0; c < 10; c++) part[c] += be[c];
        float m = part[0];
        #pragma unroll
        for (int c = 1; c < 10; c++) m = fmaxf(m, part[c]);
        float e[10], s = 0.f;
        #pragma unroll
        for (int c = 0; c < 10; c++){ e[c] = __expf(part[c] - m); s += e[c]; }
        float inv = 1.f / s;
        #pragma unroll
        for (int c = 0; c < 10; c++){
            float p = e[c] * inv;
            if (f) ((float*)out)[g*10 + c] = p;
            else   ((u16*)out)[g*10 + c]  = f2bf(p);
        }
    }
}

// ---------------------------------------------------------------------------
extern "C" void kernel_launch(void* const* d_in, const int* in_sizes, int n_in,
                              void* d_out, int out_size, void* d_ws, size_t ws_size,
                              hipStream_t stream)
{
    const int* src = (const int*)d_in[0];
    const int* dst = (const int*)d_in[1];

    char* ws = (char*)d_ws;
    size_t o = 0;
    float* canon    = (float*)(ws + o); o += ((size_t)cEND * 4 + 15) & ~(size_t)15;
    u16*   W2T      = (u16*)  (ws + o); o += (size_t)HID * HID * 2;
    u16*   WTa      = (u16*)  (ws + o); o += ((size_t)T_END * 2 + 15) & ~(size_t)15;
    u16*   X1hi     = (u16*)  (ws + o); o += (size_t)NG * 512 * 2;
    u16*   X1lo     = (u16*)  (ws + o); o += (size_t)NG * 512 * 2;
    u16*   X2hi     = (u16*)  (ws + o); o += (size_t)NG * 1024 * 2;
    u16*   X2lo     = (u16*)  (ws + o); o += (size_t)NG * 1024 * 2;
    u16*   X3hi     = (u16*)  (ws + o); o += (size_t)NG * 1024 * 2;
    u16*   X3lo     = (u16*)  (ws + o); o += (size_t)NG * 1024 * 2;
    u16*   X4hi     = (u16*)  (ws + o); o += (size_t)NG * 512 * 2;
    u16*   X4lo     = (u16*)  (ws + o); o += (size_t)NG * 512 * 2;
    o = (o + 15) & ~(size_t)15;
    u8*    AG8      = (u8*)   (ws + o); o += (size_t)NG * GROWS * SPAD;
    float* tioG     = (float*)(ws + o); o += (size_t)NG * 608 * 4;
    (void)ws_size; (void)in_sizes; (void)n_in; (void)out_size;

    // prep: tiled transposes + canon copies
    PrepIn pin;
    for (int i = 0; i < 14; i++) pin.p[i] = d_in[2 + i];
    k_prep2<<<dim3(566), dim3(256), 0, stream>>>(pin, canon, W2T, WTa);

    const float *W1 = canon+cW1, *b1 = canon+cb1, *b2 = canon+cb2;
    const float *ba = canon+cba, *bb = canon+cbb, *bc = canon+cbc, *bd = canon+cbd;
    const float *We = canon+cWe, *be = canon+cbe;

    // build: all graph-topology atomics at high occupancy (3 blocks/CU)
    k_build<<<dim3(NG), dim3(512), 0, stream>>>(src, dst, AG8, tioG);

    // mega: pure-GEMM slice loop + fused mlp_a, 2 blocks/CU
    k_mega<<<dim3(NG), dim3(512), 0, stream>>>(AG8, tioG, W1, b1, b2, W2T,
                                               WTa + T_Wa, ba, X1hi, X1lo);

    // MLP: 4-way K-split, 512-block grids
    k_mlp6<512,  2><<<dim3(32, 16), dim3(512), 0, stream>>>(X1hi, X1lo, WTa + T_Wb, bb, X2hi, X2lo, 1024);
    k_mlp6<1024, 2><<<dim3(32, 16), dim3(512), 0, stream>>>(X2hi, X2lo, WTa + T_Wc, bc, X3hi, X3lo, 1024);
    k_mlp6<1024, 1><<<dim3(32, 16), dim3(512), 0, stream>>>(X3hi, X3lo, WTa + T_Wd, bd, X4hi, X4lo, 512);

    // head + softmax
    k_head<<<dim3(NG), dim3(64), 0, stream>>>(X4hi, X4lo, We, be, d_out, (const u16*)d_in[2]);
}

// Round 4
// 184.343 us; speedup vs baseline: 1.3926x; 1.0763x over previous
//
#include <hip/hip_runtime.h>
#include <stdint.h>

typedef unsigned short u16;
typedef unsigned char  u8;
typedef unsigned int   u32;

#define NG   512
#define NPG  200
#define EPG  6400
#define HID  128
#define CS   136          // h1t row stride in u16 ([v][c], 272B rows, 16B aligned)
#define MS   232          // M row stride in u16 ([cout][s], 464B rows, 16B aligned)
#define SR   50           // dst rows per slice (4 slices, padded to 64 for MFMA)
#define SPAD 232          // count-matrix row stride (u8)
#define GROWS 216         // per-graph row allocation (200 real + slack for padded reads)

__device__ __forceinline__ float bf2f(u16 b){ u32 u = ((u32)b) << 16; return __builtin_bit_cast(float, u); }
__device__ __forceinline__ u16 f2bf(float f){
    u32 u = __builtin_bit_cast(u32, f);
    u = (u + 0x7FFFu + ((u >> 16) & 1u)) >> 16;
    return (u16)u;
}

typedef __attribute__((ext_vector_type(8))) short bf16x8;
typedef __attribute__((ext_vector_type(4))) float f32x4;

// canon arena (fp32): vectors only
enum : int { cW1=0, cb1=128, cb2=256, cba=384, cbb=896, cbc=1920, cbd=2944, cWe=3456, cbe=8576, cEND=8586 };
// WTa arena (bf16 [n][k])
enum : int { T_Wa=0, T_Wb=65536, T_Wc=589824, T_Wd=1638400, T_END=2162688 };

// ---------------------------------------------------------------------------
// K_pb: fused prep + build (independent work, disjoint block ranges).
//  blocks 0..511    : per-graph topology build (LDS atomics at 3 blocks/CU)
//  blocks 512..1043 : LDS-tiled weight transposes (vectorized both phases)
//  blocks 1044..1060: canon vector copies
// Build outputs AG8[g][216][232] u8 counts + tioG[g][608] = {t, io, ii}.
// t computed FROM the count matrix (row-dot with sVal) - no float atomics.
// ---------------------------------------------------------------------------
struct PrepIn { const void* p[14]; };

__global__ __launch_bounds__(512) void k_pb(PrepIn in,
    const int* __restrict__ src, const int* __restrict__ dst,
    float* __restrict__ canon, u16* __restrict__ W2T, u16* __restrict__ WTa,
    u8* __restrict__ AG8, float* __restrict__ tioG)
{
    __shared__ __align__(16) u32 shm[12600];   // 50400 B -> 3 blocks/CU
    const int tid = threadIdx.x;
    const int bid = blockIdx.x;

    if (bid < 512){
        // ---------------- build ----------------
        u32*   cnt  = shm;                       // 11600 u32 = 200x232 u8
        u32*   dio  = shm + 11600;               // 200 (in<<16 | out)
        float* sVal = (float*)(shm + 11800);
        float* ioL  = (float*)(shm + 12000);
        float* iiL  = (float*)(shm + 12200);
        const int g = bid;

        uint4* c4 = (uint4*)cnt;
        #pragma unroll
        for (int i = 0; i < 6; i++){
            int idx = i*512 + tid;
            if (idx < 2900) c4[idx] = make_uint4(0,0,0,0);
        }
        if (tid < NPG) dio[tid] = 0u;
        __syncthreads();

        const int ebase = g * EPG;
        const int2* s2 = (const int2*)(src + ebase);
        const int2* d2 = (const int2*)(dst + ebase);
        // single pass: degrees + counts
        #pragma unroll
        for (int i = 0; i < 7; i++){
            int e = i*512 + tid;
            if (e < EPG/2){
                int2 ss = s2[e], dd = d2[e];
                int s0 = ss.x - g*NPG, d0 = dd.x - g*NPG;
                int s1 = ss.y - g*NPG, d1 = dd.y - g*NPG;
                atomicAdd(&dio[s0], 1u);  atomicAdd(&dio[d0], 0x10000u);
                atomicAdd(&dio[s1], 1u);  atomicAdd(&dio[d1], 0x10000u);
                int i0 = d0*SPAD + s0, i1 = d1*SPAD + s1;
                atomicAdd(&cnt[i0 >> 2], 1u << (8*(i0 & 3)));
                atomicAdd(&cnt[i1 >> 2], 1u << (8*(i1 & 3)));
            }
        }
        __syncthreads();
        if (tid < NPG){
            u32 u = dio[tid];
            float din = (float)(u >> 16), dout = (float)(u & 0xFFFFu);
            float ii = rsqrtf(fmaxf(din, 1.f));
            float io = rsqrtf(fmaxf(dout, 1.f));
            iiL[tid] = ii; ioL[tid] = io;
            sVal[tid] = din * io;          // h0 = in_deg; s = h0*inv_out
        }
        __syncthreads();
        // t[d] = ii[d] * sum_s cnt[d][s]*sVal[s]  (row-dot, replaces atomics)
        if (tid < NPG){
            const u32* row = cnt + tid*(SPAD/4);
            float acc = 0.f;
            #pragma unroll
            for (int j = 0; j < 50; j++){
                u32 wv = row[j];
                acc = fmaf((float)( wv        & 0xFFu), sVal[4*j+0], acc);
                acc = fmaf((float)((wv >>  8) & 0xFFu), sVal[4*j+1], acc);
                acc = fmaf((float)((wv >> 16) & 0xFFu), sVal[4*j+2], acc);
                acc = fmaf((float)( wv >> 24        ), sVal[4*j+3], acc);
            }
            tioG[(size_t)g*608 + tid]       = acc * iiL[tid];
            tioG[(size_t)g*608 + 200 + tid] = ioL[tid];
            tioG[(size_t)g*608 + 400 + tid] = iiL[tid];
        }
        // copy counts out (pass-1 barrier already made cnt coherent)
        uint4* dq = (uint4*)(AG8 + (size_t)g*GROWS*SPAD);
        #pragma unroll
        for (int i = 0; i < 6; i++){
            int idx = i*512 + tid;
            if (idx < 2900) dq[idx] = c4[idx];
        }
    } else {
        // ---------------- prep ----------------
        u16* tile  = (u16*)shm;                  // [64][72]
        int* sflag = (int*)(shm + 12599);
        if (tid < 64){
            const u16* wb = (const u16*)in.p[0];
            u16 a = wb[tid], b = wb[64 + tid];
            unsigned long long m1 = __ballot((int)((a >> 7) & 0xFF) >= 0x7F);
            unsigned long long m2 = __ballot((int)((b >> 7) & 0xFF) >= 0x7F);
            if (tid == 0) *sflag = (__popcll(m1) + __popcll(m2) > 4) ? 1 : 0;
        }
        __syncthreads();
        const int f = *sflag;
        const int pb = bid - 512;

        if (pb < 532){
            const void* s; u16* dst_; int K, N, t, lgn;
            if      (pb < 4)  { t = pb;       s = in.p[2];  dst_ = W2T;        K = 128;  N = 128;  lgn = 1; }
            else if (pb < 20) { t = pb - 4;   s = in.p[4];  dst_ = WTa + T_Wa; K = 128;  N = 512;  lgn = 3; }
            else if (pb < 148){ t = pb - 20;  s = in.p[6];  dst_ = WTa + T_Wb; K = 512;  N = 1024; lgn = 4; }
            else if (pb < 404){ t = pb - 148; s = in.p[8];  dst_ = WTa + T_Wc; K = 1024; N = 1024; lgn = 4; }
            else              { t = pb - 404; s = in.p[10]; dst_ = WTa + T_Wd; K = 1024; N = 512;  lgn = 3; }
            const int k0 = (t >> lgn) * 64, n0 = (t & ((1 << lgn) - 1)) * 64;
            #pragma unroll
            for (int i = 0; i < 2; i++){
                int idx = i*512 + tid;               // 64 kk x 16 nn-groups
                int kk = idx >> 4, nn0 = (idx & 15)*4;
                int si = (k0 + kk)*N + n0 + nn0;
                if (f){
                    float4 fv = *(const float4*)&((const float*)s)[si];
                    tile[(nn0+0)*72+kk] = f2bf(fv.x); tile[(nn0+1)*72+kk] = f2bf(fv.y);
                    tile[(nn0+2)*72+kk] = f2bf(fv.z); tile[(nn0+3)*72+kk] = f2bf(fv.w);
                } else {
                    uint2 uv = *(const uint2*)&((const u16*)s)[si];
                    tile[(nn0+0)*72+kk] = (u16)(uv.x & 0xFFFF); tile[(nn0+1)*72+kk] = (u16)(uv.x >> 16);
                    tile[(nn0+2)*72+kk] = (u16)(uv.y & 0xFFFF); tile[(nn0+3)*72+kk] = (u16)(uv.y >> 16);
                }
            }
            __syncthreads();
            #pragma unroll
            for (int i = 0; i < 2; i++){
                int idx = i*512 + tid;               // 64 nn x 16 kk-groups
                int nn = idx >> 4, kk0 = (idx & 15)*4;
                uint2 val = *(const uint2*)&tile[nn*72 + kk0];
                *(uint2*)&dst_[(size_t)(n0 + nn)*K + k0 + kk0] = val;
            }
        } else {
            int i = (pb - 532)*512 + tid;
            if (i < cEND){
                const void* s; int off;
                if      (i < 128) { s = in.p[0];  off = i; }
                else if (i < 256) { s = in.p[1];  off = i - 128; }
                else if (i < 384) { s = in.p[3];  off = i - 256; }
                else if (i < 896) { s = in.p[5];  off = i - 384; }
                else if (i < 1920){ s = in.p[7];  off = i - 896; }
                else if (i < 2944){ s = in.p[9];  off = i - 1920; }
                else if (i < 3456){ s = in.p[11]; off = i - 2944; }
                else if (i < 8576){ s = in.p[12]; off = i - 3456; }
                else              { s = in.p[13]; off = i - 8576; }
                canon[i] = f ? ((const float*)s)[off] : bf2f(((const u16*)s)[off]);
            }
        }
    }
}

// ---------------------------------------------------------------------------
// K_mega v5: M-restructure. H = cnt @ M^T with M[cout][s] = sum_c h1[s][c]W2[c][cout]
// computed ONCE per graph, so the 4-slice loop is barrier-free:
//  P4    : h1t[v][c] (bf16, scaled, [224][CS]) in HB
//  M-GEMM: Mt frags (m=s, n=cout) from h1t rows + W2T rows; written TRANSPOSED
//          in-place over HB as M[cout][s] (C-write layout is ours to choose)
//  slices: A-frags = u8 counts from global AG8 (reg convert), B-frags = M rows
//          from LDS, epilogue relu/ii/pool in registers. NO barriers, no Zs.
//  tail  : pool quad-reduce + fused mlp_a (X1 = relu(pool/200 @ Wa + ba))
// Barriers: 5 total (was 11). LDS 65.4 KB -> 2 blocks/CU.
// A-frag: A[m=lr][k=quad*8+j]; B-frag: B[k=quad*8+j][n=lr]; C/D: col=lr,row=quad*4+r
// ---------------------------------------------------------------------------
__global__ __launch_bounds__(512, 4) void k_mega(
    const u8* __restrict__ AG8, const float* __restrict__ tioG,
    const float* __restrict__ W1, const float* __restrict__ b1,
    const float* __restrict__ b2, const u16* __restrict__ W2T,
    const u16* __restrict__ WTaA, const float* __restrict__ ba,
    u16* __restrict__ X1hi, u16* __restrict__ X1lo)
{
    __shared__ __align__(16) u16 HB[224*CS];       // 60928 B: h1t, then M
    __shared__ float tL[NPG], ioL[NPG], iiL[NPG];
    __shared__ __align__(16) float w1L[HID], b1L[HID];
    __shared__ float b2L[HID];
    __shared__ __align__(16) float poolL[HID];
    // total 65376 B -> 2 blocks/CU

    const int g = blockIdx.x, tid = threadIdx.x;
    if (tid < NPG){
        tL[tid]  = tioG[(size_t)g*608 + tid];
        ioL[tid] = tioG[(size_t)g*608 + 200 + tid];
        iiL[tid] = tioG[(size_t)g*608 + 400 + tid];
    }
    if (tid < HID){ w1L[tid] = W1[tid]; b1L[tid] = b1[tid]; b2L[tid] = b2[tid]; poolL[tid] = 0.f; }
    __syncthreads();

    // P4: h1t[v][c] = bf16( relu(t*w1+b1) * io ), rows v>=200 zero
    #pragma unroll
    for (int i = 0; i < 7; i++){
        int idx = i*512 + tid;                     // 224 rows x 16 c-groups
        int v = idx >> 4, c0 = (idx & 15)*8;
        bf16x8 out = {0,0,0,0,0,0,0,0};
        if (v < NPG){
            float tv = tL[v], iov = ioL[v];
            float4 wa = *(const float4*)&w1L[c0];
            float4 wb = *(const float4*)&w1L[c0+4];
            float4 bA = *(const float4*)&b1L[c0];
            float4 bB = *(const float4*)&b1L[c0+4];
            float ww[8] = {wa.x, wa.y, wa.z, wa.w, wb.x, wb.y, wb.z, wb.w};
            float bb[8] = {bA.x, bA.y, bA.z, bA.w, bB.x, bB.y, bB.z, bB.w};
            #pragma unroll
            for (int j = 0; j < 8; j++)
                out[j] = (short)f2bf(fmaxf(fmaf(tv, ww[j], bb[j]), 0.f) * iov);
        }
        *(bf16x8*)&HB[v*CS + c0] = out;
    }
    __syncthreads();

    const int w = tid >> 6, lane = tid & 63;
    const int lr = lane & 15, quad = lane >> 4;
    const int wA = w >> 2, wB = w & 3;             // wA: s/v-half; wB: cout-group
    const f32x4 fz = {0.f, 0.f, 0.f, 0.f};

    // M-GEMM: Mt[s=224][cout=128] = h1t @ W2 ; wave = 7 m-frags x 2 n-frags
    f32x4 accM[7][2];
    #pragma unroll
    for (int mi = 0; mi < 7; mi++){ accM[mi][0] = fz; accM[mi][1] = fz; }
    #pragma unroll
    for (int ks = 0; ks < 4; ks++){
        bf16x8 bw[2];
        #pragma unroll
        for (int nt = 0; nt < 2; nt++)
            bw[nt] = *(const bf16x8*)&W2T[(size_t)(wB*32 + nt*16 + lr)*HID + ks*32 + quad*8];
        #pragma unroll
        for (int mi = 0; mi < 7; mi++){
            bf16x8 ah = *(const bf16x8*)&HB[(wA*112 + mi*16 + lr)*CS + ks*32 + quad*8];
            #pragma unroll
            for (int nt = 0; nt < 2; nt++)
                accM[mi][nt] = __builtin_amdgcn_mfma_f32_16x16x32_bf16(ah, bw[nt], accM[mi][nt], 0, 0, 0);
        }
    }
    __syncthreads();   // all h1t reads complete before overwrite

    // write M[cout][s] (transposed C-write): 4 s-consecutive values -> b64
    #pragma unroll
    for (int mi = 0; mi < 7; mi++)
        #pragma unroll
        for (int nt = 0; nt < 2; nt++){
            int cout = wB*32 + nt*16 + lr;
            int s0   = wA*112 + mi*16 + quad*4;
            u16 z0 = f2bf(accM[mi][nt][0]), z1 = f2bf(accM[mi][nt][1]);
            u16 z2 = f2bf(accM[mi][nt][2]), z3 = f2bf(accM[mi][nt][3]);
            uint2 pk = { (u32)z0 | ((u32)z1 << 16), (u32)z2 | ((u32)z3 << 16) };
            *(uint2*)&HB[cout*MS + s0] = pk;
        }
    __syncthreads();   // M ready; slice loop below is barrier-free

    const float b2c[2] = { b2L[wB*32 + lr], b2L[wB*32 + 16 + lr] };
    float pacc[2] = {0.f, 0.f};
    const u8* Abase = AG8 + (size_t)g*GROWS*SPAD;

    // counts double-buffer: rows v = wA*32 + mi*16 + lr of slice q
    uint2 brA[2][7], brB[2][7];
    #pragma unroll
    for (int mi = 0; mi < 2; mi++)
        #pragma unroll
        for (int ks = 0; ks < 7; ks++)
            brA[mi][ks] = *(const uint2*)(Abase + (size_t)(wA*32 + mi*16 + lr)*SPAD + ks*32 + quad*8);

    for (int q = 0; q < 4; q++){
        if (q < 3){
            #pragma unroll
            for (int mi = 0; mi < 2; mi++)
                #pragma unroll
                for (int ks = 0; ks < 7; ks++)
                    brB[mi][ks] = *(const uint2*)(Abase + (size_t)((q+1)*SR + wA*32 + mi*16 + lr)*SPAD + ks*32 + quad*8);
        }
        f32x4 acc[2][2] = {{fz, fz}, {fz, fz}};
        #pragma unroll
        for (int ks = 0; ks < 7; ks++){
            bf16x8 bm[2];
            #pragma unroll
            for (int nt = 0; nt < 2; nt++)
                bm[nt] = *(const bf16x8*)&HB[(wB*32 + nt*16 + lr)*MS + ks*32 + quad*8];
            #pragma unroll
            for (int mi = 0; mi < 2; mi++){
                u32 lo = brA[mi][ks].x, hi = brA[mi][ks].y;
                bf16x8 am;
                #pragma unroll
                for (int j = 0; j < 4; j++){   // u8 -> bf16 exact (ints<256 truncate clean)
                    am[j]   = (short)(u16)(__builtin_bit_cast(u32, (float)((lo >> (8*j)) & 0xFFu)) >> 16);
                    am[j+4] = (short)(u16)(__builtin_bit_cast(u32, (float)((hi >> (8*j)) & 0xFFu)) >> 16);
                }
                #pragma unroll
                for (int nt = 0; nt < 2; nt++)
                    acc[mi][nt] = __builtin_amdgcn_mfma_f32_16x16x32_bf16(am, bm[nt], acc[mi][nt], 0, 0, 0);
            }
        }
        // epilogue: pacc += relu(H*ii + b2) for real rows
        #pragma unroll
        for (int mi = 0; mi < 2; mi++)
            #pragma unroll
            for (int nt = 0; nt < 2; nt++)
                #pragma unroll
                for (int r = 0; r < 4; r++){
                    int vq = wA*32 + mi*16 + quad*4 + r;
                    if (vq < SR)
                        pacc[nt] += fmaxf(fmaf(acc[mi][nt][r], iiL[q*SR + vq], b2c[nt]), 0.f);
                }
        #pragma unroll
        for (int mi = 0; mi < 2; mi++)
            #pragma unroll
            for (int ks = 0; ks < 7; ks++) brA[mi][ks] = brB[mi][ks];
    }

    // pool reduce: quads via shuffle, then 1 atomic per 16 lanes per nt
    #pragma unroll
    for (int nt = 0; nt < 2; nt++){
        float v = pacc[nt];
        v += __shfl_down(v, 32);
        v += __shfl_down(v, 16);
        if (quad == 0) atomicAdd(&poolL[wB*32 + nt*16 + lr], v);
    }
    __syncthreads();

    // fused mlp_a: X1[g][c=tid] = relu( (pool/200) . Wa[:,c] + ba[c] ), fp32 dot
    {
        const u16* wrow = WTaA + (size_t)tid * HID;   // WTa row-major [512][128]
        float dot = 0.f;
        #pragma unroll
        for (int kk = 0; kk < HID; kk += 8){
            bf16x8 wv = *(const bf16x8*)&wrow[kk];
            float4 p0 = *(const float4*)&poolL[kk];
            float4 p1 = *(const float4*)&poolL[kk + 4];
            float pp[8] = {p0.x, p0.y, p0.z, p0.w, p1.x, p1.y, p1.z, p1.w};
            #pragma unroll
            for (int j = 0; j < 8; j++)
                dot = fmaf(pp[j], bf2f((u16)wv[j]), dot);
        }
        float v = fmaxf(dot * (1.f/NPG) + ba[tid], 0.f);
        u16 hh = f2bf(v);
        X1hi[(size_t)g*512 + tid] = hh;
        X1lo[(size_t)g*512 + tid] = f2bf(v - bf2f(hh));
    }
}

// ---------------------------------------------------------------------------
// MLP layer v6: 4-way K-split, tile 16 x (NFR*32), 512-block grids ->
// 2 blocks/CU, 16 waves/CU. hi/lo bf16 split MFMA, depth-1 prefetch.
// ---------------------------------------------------------------------------
template<int K, int NFR>
__global__ __launch_bounds__(512) void k_mlp6(
    const u16* __restrict__ Ahi, const u16* __restrict__ Alo,
    const u16* __restrict__ WT, const float* __restrict__ bias,
    u16* __restrict__ Ohi, u16* __restrict__ Olo, int Nc)
{
    constexpr int KQ = K/4, ITERS = KQ/32, NTILE = NFR*32;
    __shared__ __align__(16) float red[3][16][68];

    const int tid = threadIdx.x;
    const int w = tid >> 6, lane = tid & 63;
    const int kz = w >> 1, wn = w & 1;
    const int lr = lane & 15, quad = lane >> 4;
    const int row0 = blockIdx.x * 16, col0 = blockIdx.y * NTILE;
    const size_t m = row0 + lr;
    const int k0 = kz * KQ;

    auto loadA = [&](int it, bf16x8& hi, bf16x8& lo){
        const int kk = k0 + it*32 + quad*8;
        hi = *(const bf16x8*)&Ahi[m*K + kk];
        lo = *(const bf16x8*)&Alo[m*K + kk];
    };
    auto loadB = [&](int it, bf16x8* b){
        const int kk = k0 + it*32 + quad*8;
        #pragma unroll
        for (int nt = 0; nt < NFR; nt++){
            int n = col0 + wn*(NFR*16) + nt*16 + lr;
            b[nt] = *(const bf16x8*)&WT[(size_t)n*K + kk];
        }
    };

    const f32x4 fz = {0.f, 0.f, 0.f, 0.f};
    f32x4 acc[NFR];
    #pragma unroll
    for (int nt = 0; nt < NFR; nt++) acc[nt] = fz;
    bf16x8 chi, clo, cb[NFR], nhi, nlo, nb[NFR];
    loadA(0, chi, clo); loadB(0, cb);
    #pragma unroll
    for (int it = 0; it < ITERS; it++){
        if (it + 1 < ITERS){ loadA(it+1, nhi, nlo); loadB(it+1, nb); }
        #pragma unroll
        for (int nt = 0; nt < NFR; nt++){
            acc[nt] = __builtin_amdgcn_mfma_f32_16x16x32_bf16(chi, cb[nt], acc[nt], 0, 0, 0);
            acc[nt] = __builtin_amdgcn_mfma_f32_16x16x32_bf16(clo, cb[nt], acc[nt], 0, 0, 0);
        }
        chi = nhi; clo = nlo;
        #pragma unroll
        for (int nt = 0; nt < NFR; nt++) cb[nt] = nb[nt];
    }

    if (kz > 0){
        #pragma unroll
        for (int nt = 0; nt < NFR; nt++)
            #pragma unroll
            for (int r = 0; r < 4; r++)
                red[kz-1][quad*4 + r][wn*(NFR*16) + nt*16 + lr] = acc[nt][r];
    }
    __syncthreads();
    if (kz == 0){
        #pragma unroll
        for (int nt = 0; nt < NFR; nt++)
            #pragma unroll
            for (int r = 0; r < 4; r++){
                int rr = quad*4 + r;
                int cc = wn*(NFR*16) + nt*16 + lr;
                float v = acc[nt][r] + red[0][rr][cc] + red[1][rr][cc] + red[2][rr][cc]
                        + bias[col0 + cc];
                v = fmaxf(v, 0.f);
                u16 hh = f2bf(v);
                size_t go = (size_t)(row0 + rr) * Nc + col0 + cc;
                Ohi[go] = hh;
                Olo[go] = f2bf(v - bf2f(hh));
            }
    }
}

// ---------------------------------------------------------------------------
// head: logits = (X4hi+X4lo) @ We + be; softmax -> out (dtype derived inline)
// ---------------------------------------------------------------------------
__global__ __launch_bounds__(64) void k_head(
    const u16* __restrict__ Xhi, const u16* __restrict__ Xlo,
    const float* __restrict__ We, const float* __restrict__ be,
    void* __restrict__ out, const u16* __restrict__ w1bits)
{
    const int g = blockIdx.x, lane = threadIdx.x;
    u16 a = w1bits[lane], b = w1bits[64 + lane];
    unsigned long long m1 = __ballot((int)((a >> 7) & 0xFF) >= 0x7F);
    unsigned long long m2 = __ballot((int)((b >> 7) & 0xFF) >= 0x7F);
    const int f = (__popcll(m1) + __popcll(m2) > 4) ? 1 : 0;

    float part[10];
    #pragma unroll
    for (int c = 0; c < 10; c++) part[c] = 0.f;
    for (int k = lane; k < 512; k += 64){
        float x = bf2f(Xhi[(size_t)g*512 + k]) + bf2f(Xlo[(size_t)g*512 + k]);
        #pragma unroll
        for (int c = 0; c < 10; c++) part[c] = fmaf(x, We[k*10 + c], part[c]);
    }
    #pragma unroll
    for (int c = 0; c < 10; c++){
        float v = part[c];
        for (int off = 32; off > 0; off >>= 1) v += __shfl_down(v, off);
        part[c] = v;
    }
    if (lane == 0){
        #pragma unroll
        for (int c = 0; c < 10; c++) part[c] += be[c];
        float m = part[0];
        #pragma unroll
        for (int c = 1; c < 10; c++) m = fmaxf(m, part[c]);
        float e[10], s = 0.f;
        #pragma unroll
        for (int c = 0; c < 10; c++){ e[c] = __expf(part[c] - m); s += e[c]; }
        float inv = 1.f / s;
        #pragma unroll
        for (int c = 0; c < 10; c++){
            float p = e[c] * inv;
            if (f) ((float*)out)[g*10 + c] = p;
            else   ((u16*)out)[g*10 + c]  = f2bf(p);
        }
    }
}

// ---------------------------------------------------------------------------
extern "C" void kernel_launch(void* const* d_in, const int* in_sizes, int n_in,
                              void* d_out, int out_size, void* d_ws, size_t ws_size,
                              hipStream_t stream)
{
    const int* src = (const int*)d_in[0];
    const int* dst = (const int*)d_in[1];

    char* ws = (char*)d_ws;
    size_t o = 0;
    float* canon    = (float*)(ws + o); o += ((size_t)cEND * 4 + 15) & ~(size_t)15;
    u16*   W2T      = (u16*)  (ws + o); o += (size_t)HID * HID * 2;
    u16*   WTa      = (u16*)  (ws + o); o += ((size_t)T_END * 2 + 15) & ~(size_t)15;
    u16*   X1hi     = (u16*)  (ws + o); o += (size_t)NG * 512 * 2;
    u16*   X1lo     = (u16*)  (ws + o); o += (size_t)NG * 512 * 2;
    u16*   X2hi     = (u16*)  (ws + o); o += (size_t)NG * 1024 * 2;
    u16*   X2lo     = (u16*)  (ws + o); o += (size_t)NG * 1024 * 2;
    u16*   X3hi     = (u16*)  (ws + o); o += (size_t)NG * 1024 * 2;
    u16*   X3lo     = (u16*)  (ws + o); o += (size_t)NG * 1024 * 2;
    u16*   X4hi     = (u16*)  (ws + o); o += (size_t)NG * 512 * 2;
    u16*   X4lo     = (u16*)  (ws + o); o += (size_t)NG * 512 * 2;
    o = (o + 15) & ~(size_t)15;
    u8*    AG8      = (u8*)   (ws + o); o += (size_t)NG * GROWS * SPAD;
    float* tioG     = (float*)(ws + o); o += (size_t)NG * 608 * 4;
    (void)ws_size; (void)in_sizes; (void)n_in; (void)out_size;

    // fused prep + build (independent block ranges, one dispatch)
    PrepIn pin;
    for (int i = 0; i < 14; i++) pin.p[i] = d_in[2 + i];
    k_pb<<<dim3(1061), dim3(512), 0, stream>>>(pin, src, dst, canon, W2T, WTa, AG8, tioG);

    const float *W1 = canon+cW1, *b1 = canon+cb1, *b2 = canon+cb2;
    const float *ba = canon+cba, *bb = canon+cbb, *bc = canon+cbc, *bd = canon+cbd;
    const float *We = canon+cWe, *be = canon+cbe;

    // mega: M-restructured, barrier-free slice loop + fused mlp_a
    k_mega<<<dim3(NG), dim3(512), 0, stream>>>(AG8, tioG, W1, b1, b2, W2T,
                                               WTa + T_Wa, ba, X1hi, X1lo);

    // MLP: 4-way K-split, 512-block grids
    k_mlp6<512,  2><<<dim3(32, 16), dim3(512), 0, stream>>>(X1hi, X1lo, WTa + T_Wb, bb, X2hi, X2lo, 1024);
    k_mlp6<1024, 2><<<dim3(32, 16), dim3(512), 0, stream>>>(X2hi, X2lo, WTa + T_Wc, bc, X3hi, X3lo, 1024);
    k_mlp6<1024, 1><<<dim3(32, 16), dim3(512), 0, stream>>>(X3hi, X3lo, WTa + T_Wd, bd, X4hi, X4lo, 512);

    // head + softmax
    k_head<<<dim3(NG), dim3(64), 0, stream>>>(X4hi, X4lo, We, be, d_out, (const u16*)d_in[2]);
}